// Round 2
// baseline (7419.678 us; speedup 1.0000x reference)
//
#include <hip/hip_runtime.h>
#include <hip/hip_bf16.h>
#include <math.h>

typedef __hip_bfloat16 bf16;

#define BD 256   // batch
#define NN 128   // tokens
#define DM 256   // model dim
#define NHD 4    // heads
#define HDIM 64  // head dim
#define RR 3     // rounds

__device__ __forceinline__ float b2f(bf16 x) { return __bfloat162float(x); }
__device__ __forceinline__ bf16 f2b(float x) { return __float2bfloat16(x); }
__device__ __forceinline__ float geluf(float x) { return 0.5f * x * (1.f + erff(x * 0.70710678118654752f)); }

// fp32 -> bf16 convert (H -> Hcur)
__global__ __launch_bounds__(256) void cvt32to16_kernel(
    const float* __restrict__ in, bf16* __restrict__ out, int n)
{
  int i = blockIdx.x * 256 + threadIdx.x;
  int stride = gridDim.x * 256;
  for (; i < n; i += stride) out[i] = f2b(in[i]);
}

// bf16 -> fp32 (final Hr -> d_out)
__global__ __launch_bounds__(256) void cvt16to32_kernel(
    const bf16* __restrict__ in, float* __restrict__ out, int n)
{
  int i = blockIdx.x * 256 + threadIdx.x;
  int stride = gridDim.x * 256;
  for (; i < n; i += stride) out[i] = b2f(in[i]);
}

// ---------------------------------------------------------------------------
// Generic GEMM: out[b, m, c] = act( sum_k A[b, row(m), k] * W[k, c] + bias[c] )
// A bf16 [B,N,256] (A2 optional second concat half for K=512); W,bias fp32.
// gather (optional): row(m) = clip(gather[b,m], 0, N-1)
// grid (N/16, B), block 256 (thread = output column c). fp32 accumulate.
// ---------------------------------------------------------------------------
__global__ __launch_bounds__(256) void gemm256_kernel(
    const bf16* __restrict__ A1, const bf16* __restrict__ A2,
    const int* __restrict__ gather, const float* __restrict__ W,
    const float* __restrict__ bias, bf16* __restrict__ out,
    int K, int act)
{
  const int b = blockIdx.y;
  const int m0 = blockIdx.x * 16;
  const int c = threadIdx.x;
  __shared__ float a_sh[16][512];

  for (int idx = threadIdx.x; idx < 16 * K; idx += 256) {
    int m = idx / K, k = idx - m * K;
    int row = m0 + m;
    if (gather) { int g = gather[(size_t)b * NN + row]; row = min(max(g, 0), NN - 1); }
    float v = (k < 256) ? b2f(A1[((size_t)b * NN + row) * DM + k])
                        : b2f(A2[((size_t)b * NN + row) * DM + (k - 256)]);
    a_sh[m][k] = v;
  }
  __syncthreads();

  float acc[16];
#pragma unroll
  for (int m = 0; m < 16; m++) acc[m] = 0.f;

  for (int k = 0; k < K; k += 4) {
    float w0 = W[(size_t)(k + 0) * DM + c];
    float w1 = W[(size_t)(k + 1) * DM + c];
    float w2 = W[(size_t)(k + 2) * DM + c];
    float w3 = W[(size_t)(k + 3) * DM + c];
#pragma unroll
    for (int m = 0; m < 16; m++) {
      float4 a = *(const float4*)&a_sh[m][k];
      acc[m] += a.x * w0 + a.y * w1 + a.z * w2 + a.w * w3;
    }
  }

  float bb = bias ? bias[c] : 0.f;
#pragma unroll
  for (int m = 0; m < 16; m++) {
    float x = acc[m] + bb;
    if (act == 1) x = geluf(x);
    out[((size_t)b * NN + m0 + m) * DM + c] = f2b(x);
  }
}

// ---------------------------------------------------------------------------
// Fused attention for one (batch, head). Q,K,V bf16 [B,N,256], head h in
// cols h*64..h*64+63.  ph!=null => sibling mask: keep only
// (ph[q]==ph[t]) && q!=t && mask[q]>0 && mask[t]>0, else -1e9.
// grid (NH, B), block 128 (thread = key index t).
// ---------------------------------------------------------------------------
__global__ __launch_bounds__(128) void attn_kernel(
    const bf16* __restrict__ Qb, const bf16* __restrict__ Kb, const bf16* __restrict__ Vb,
    const int* __restrict__ ph, const float* __restrict__ mask,
    bf16* __restrict__ Ob)
{
  const int b = blockIdx.y, h = blockIdx.x;
  const int t = threadIdx.x;
  __shared__ bf16 Ksh[NN][66];   // pad 66: 2-way banks (free)
  __shared__ bf16 Vsh[NN][66];
  __shared__ float q_sh[HDIM];
  __shared__ float p_sh[NN];
  __shared__ float red[2];
  __shared__ float opart[2][HDIM];

  for (int idx = t; idx < NN * HDIM; idx += 128) {
    int row = idx >> 6, d = idx & 63;
    size_t g = ((size_t)b * NN + row) * DM + h * HDIM + d;
    Ksh[row][d] = Kb[g];
    Vsh[row][d] = Vb[g];
  }
  int myph = 0; float mymsk = 1.f;
  if (ph) { myph = ph[(size_t)b * NN + t]; mymsk = mask[(size_t)b * NN + t]; }
  __syncthreads();

  for (int q = 0; q < NN; q++) {
    if (t < HDIM) q_sh[t] = b2f(Qb[((size_t)b * NN + q) * DM + h * HDIM + t]);
    __syncthreads();

    float s = 0.f;
#pragma unroll 8
    for (int d = 0; d < HDIM; d++) s += q_sh[d] * b2f(Ksh[t][d]);
    s *= 0.125f;  // 1/sqrt(64)
    if (ph) {
      int qph = ph[(size_t)b * NN + q];
      float qmsk = mask[(size_t)b * NN + q];
      bool sib = (qph == myph) && (q != t) && (mymsk > 0.f) && (qmsk > 0.f);
      if (!sib) s = -1e9f;
    }
    // softmax across 128 threads (2 waves)
    float mx = s;
#pragma unroll
    for (int o = 1; o < 64; o <<= 1) mx = fmaxf(mx, __shfl_xor(mx, o, 64));
    if ((t & 63) == 0) red[t >> 6] = mx;
    __syncthreads();
    mx = fmaxf(red[0], red[1]);
    float p = __expf(s - mx);
    float sm = p;
#pragma unroll
    for (int o = 1; o < 64; o <<= 1) sm += __shfl_xor(sm, o, 64);
    __syncthreads();              // red reads done before overwrite
    if ((t & 63) == 0) red[t >> 6] = sm;
    __syncthreads();
    p = p / (red[0] + red[1]);
    p_sh[t] = p;
    __syncthreads();

    int d = t & 63, half = t >> 6;
    float o_ = 0.f;
#pragma unroll 8
    for (int k = 0; k < 64; k++) {
      int kk = half * 64 + k;
      o_ += p_sh[kk] * b2f(Vsh[kk][d]);
    }
    opart[half][d] = o_;
    __syncthreads();
    if (t < HDIM)
      Ob[((size_t)b * NN + q) * DM + h * HDIM + t] = f2b(opart[0][t] + opart[1][t]);
    __syncthreads();
  }
}

// ---------------------------------------------------------------------------
// child_avg[b,m,d] = (sum_{n: hi[n]==m} Hr[b,n,d]) / max(sum_{n: hi[n]==m} mask[b,n], 1)
// grid (N/16, B), block 256 (thread = d). Deterministic (no atomics).
// ---------------------------------------------------------------------------
__global__ __launch_bounds__(256) void child_avg_kernel(
    const bf16* __restrict__ Hr, const int* __restrict__ ph, const float* __restrict__ mask,
    bf16* __restrict__ CA)
{
  const int b = blockIdx.y;
  const int m0 = blockIdx.x * 16;
  const int d = threadIdx.x;
  __shared__ int hi_sh[NN];
  __shared__ float mk_sh[NN];
  if (threadIdx.x < NN) {
    int g = ph[(size_t)b * NN + threadIdx.x];
    hi_sh[threadIdx.x] = min(max(g, 0), NN - 1);
    mk_sh[threadIdx.x] = mask[(size_t)b * NN + threadIdx.x];
  }
  __syncthreads();

  float acc[16], cnt[16];
#pragma unroll
  for (int m = 0; m < 16; m++) { acc[m] = 0.f; cnt[m] = 0.f; }
  for (int n = 0; n < NN; n++) {
    int hn = hi_sh[n];
    float v = b2f(Hr[((size_t)b * NN + n) * DM + d]);
    float mv = mk_sh[n];
#pragma unroll
    for (int m = 0; m < 16; m++) {
      bool hit = (hn == m0 + m);
      acc[m] += hit ? v : 0.f;
      cnt[m] += hit ? mv : 0.f;
    }
  }
#pragma unroll
  for (int m = 0; m < 16; m++) {
    float a = acc[m] / fmaxf(cnt[m], 1.f);
    CA[((size_t)b * NN + m0 + m) * DM + d] = f2b(a);
  }
}

// ---------------------------------------------------------------------------
// comb = [Hr, mH, mC, mS]; g=sigmoid(comb@gw+gb); u=gelu(comb@tw+tb);
// Hn = Hr + g*u; LayerNorm(Hn)*lg+lb -> Hout (in-place safe: own rows only).
// grid (N/8, B), block 256 (thread = output column c).
// ---------------------------------------------------------------------------
__global__ __launch_bounds__(256) void fuse_ln_kernel(
    const bf16* __restrict__ Hr, const bf16* __restrict__ mH,
    const bf16* __restrict__ mC, const bf16* __restrict__ mS,
    const float* __restrict__ gw, const float* __restrict__ gb,
    const float* __restrict__ tw, const float* __restrict__ tb,
    const float* __restrict__ lg, const float* __restrict__ lb,
    bf16* __restrict__ Hout)
{
  const int b = blockIdx.y;
  const int m0 = blockIdx.x * 8;
  const int c = threadIdx.x;
  __shared__ float comb[8][1024];
  __shared__ float red[8];

  for (int idx = threadIdx.x; idx < 8 * 1024; idx += 256) {
    int m = idx >> 10, k = idx & 1023;
    int seg = k >> 8, kk = k & 255;
    const bf16* src = (seg == 0) ? Hr : ((seg == 1) ? mH : ((seg == 2) ? mC : mS));
    comb[m][k] = b2f(src[((size_t)b * NN + m0 + m) * DM + kk]);
  }
  __syncthreads();

  float ag[8], au[8];
#pragma unroll
  for (int m = 0; m < 8; m++) { ag[m] = 0.f; au[m] = 0.f; }

  for (int k = 0; k < 1024; k += 4) {
    float g0 = gw[(size_t)(k + 0) * DM + c], g1 = gw[(size_t)(k + 1) * DM + c];
    float g2 = gw[(size_t)(k + 2) * DM + c], g3 = gw[(size_t)(k + 3) * DM + c];
    float t0 = tw[(size_t)(k + 0) * DM + c], t1 = tw[(size_t)(k + 1) * DM + c];
    float t2 = tw[(size_t)(k + 2) * DM + c], t3 = tw[(size_t)(k + 3) * DM + c];
#pragma unroll
    for (int m = 0; m < 8; m++) {
      float4 a = *(const float4*)&comb[m][k];
      ag[m] += a.x * g0 + a.y * g1 + a.z * g2 + a.w * g3;
      au[m] += a.x * t0 + a.y * t1 + a.z * t2 + a.w * t3;
    }
  }

  float gbv = gb[c], tbv = tb[c], lgv = lg[c], lbv = lb[c];
  int w = c >> 6, ln = c & 63;
  for (int m = 0; m < 8; m++) {
    float g = 1.f / (1.f + __expf(-(ag[m] + gbv)));
    float x = au[m] + tbv;
    float u = geluf(x);
    float hn = comb[m][c] + g * u;   // comb[m][0..255] is Hr
    float s1 = hn, s2 = hn * hn;
#pragma unroll
    for (int o = 1; o < 64; o <<= 1) { s1 += __shfl_xor(s1, o, 64); s2 += __shfl_xor(s2, o, 64); }
    if (ln == 0) { red[w] = s1; red[4 + w] = s2; }
    __syncthreads();
    float sum = red[0] + red[1] + red[2] + red[3];
    float sq  = red[4] + red[5] + red[6] + red[7];
    float mu = sum * (1.f / DM);
    float var = sq * (1.f / DM) - mu * mu;
    float y = (hn - mu) * rsqrtf(var + 1e-5f) * lgv + lbv;
    Hout[((size_t)b * NN + m0 + m) * DM + c] = f2b(y);
    __syncthreads();
  }
}

// rh[b,n] = h_head[b,n,:].bh_w + bh_b ; rd[b,n] = h_dep[b,n,:].bd_w + bd_b
__global__ __launch_bounds__(256) void rhrd_kernel(
    const bf16* __restrict__ hh, const bf16* __restrict__ hd,
    const float* __restrict__ bhw, const float* __restrict__ bhb,
    const float* __restrict__ bdw, const float* __restrict__ bdb,
    float* __restrict__ rh, float* __restrict__ rd)
{
  int b = blockIdx.x;
  int t = threadIdx.x;
  int n = t & 127;
  bool isD = t >= 128;
  const bf16* row = (isD ? hd : hh) + ((size_t)b * NN + n) * DM;
  const float* wv = isD ? bdw : bhw;
  float s = isD ? bdb[0] : bhb[0];
  for (int k = 0; k < DM; k++) s += b2f(row[k]) * wv[k];
  (isD ? rd : rh)[(size_t)b * NN + n] = s;
}

// scores[b,q,m] = tmp[b,q,:].h_dep[b,m,:] + rh[b,m] + rd[b,q]   (fp32 out)
__global__ __launch_bounds__(256) void scores_kernel(
    const bf16* __restrict__ tmp, const bf16* __restrict__ hd,
    const float* __restrict__ rh, const float* __restrict__ rd,
    float* __restrict__ out)
{
  int b = blockIdx.z;
  int q0 = blockIdx.x * 16, mm0 = blockIdx.y * 16;
  __shared__ bf16 tq[16][264];
  __shared__ bf16 tm[16][264];
  for (int idx = threadIdx.x; idx < 16 * 256; idx += 256) {
    int r = idx >> 8, k = idx & 255;
    tq[r][k] = tmp[((size_t)b * NN + q0 + r) * DM + k];
    tm[r][k] = hd[((size_t)b * NN + mm0 + r) * DM + k];
  }
  __syncthreads();
  int q = threadIdx.x >> 4, m = threadIdx.x & 15;
  float s = 0.f;
  for (int k = 0; k < DM; k++) s += b2f(tq[q][k]) * b2f(tm[m][k]);
  s += rh[(size_t)b * NN + mm0 + m] + rd[(size_t)b * NN + q0 + q];
  out[(size_t)b * NN * NN + (size_t)(q0 + q) * NN + mm0 + m] = s;
}

// ---------------------------------------------------------------------------
extern "C" void kernel_launch(void* const* d_in, const int* in_sizes, int n_in,
                              void* d_out, int out_size, void* d_ws, size_t ws_size,
                              hipStream_t stream) {
  const float* H      = (const float*)d_in[0];
  const int*   ph     = (const int*)  d_in[1];
  const float* mask   = (const float*)d_in[2];
  const float* ha_w   = (const float*)d_in[3];
  const float* ha_b   = (const float*)d_in[4];
  const float* sa_w   = (const float*)d_in[5];
  const float* sa_b   = (const float*)d_in[6];
  const float* ct_w   = (const float*)d_in[7];
  const float* ct_b   = (const float*)d_in[8];
  const float* gate_w = (const float*)d_in[9];
  const float* gate_b = (const float*)d_in[10];
  const float* tr_w   = (const float*)d_in[11];
  const float* tr_b   = (const float*)d_in[12];
  const float* ln_g   = (const float*)d_in[13];
  const float* ln_b   = (const float*)d_in[14];
  const float* ahw    = (const float*)d_in[15];
  const float* ahb    = (const float*)d_in[16];
  const float* adw    = (const float*)d_in[17];
  const float* adb    = (const float*)d_in[18];
  const float* bil    = (const float*)d_in[19];
  const float* bhw    = (const float*)d_in[20];
  const float* bhb    = (const float*)d_in[21];
  const float* bdw    = (const float*)d_in[22];
  const float* bdb    = (const float*)d_in[23];

  const size_t AB = (size_t)BD * NN * DM;  // 8,388,608 elems
  bf16* wsb  = (bf16*)d_ws;
  bf16* Hcur = wsb;
  bf16* Qb   = wsb + 1 * AB;   // also child_avg, h_head
  bf16* Kbuf = wsb + 2 * AB;   // also h_dep
  bf16* Vbuf = wsb + 3 * AB;   // also bilinear tmp
  bf16* Ob   = wsb + 4 * AB;
  bf16* mHb  = wsb + 5 * AB;
  bf16* mCb  = wsb + 6 * AB;
  bf16* mSb  = wsb + 7 * AB;
  float* rh  = (float*)(wsb + 8 * AB);
  float* rd  = rh + (size_t)BD * NN;

  cvt32to16_kernel<<<dim3(2048), 256, 0, stream>>>(H, Hcur, (int)AB);

  dim3 gG(8, BD);      // gemm grid: 8 row-tiles x batch
  for (int r = 0; r < RR; r++) {
    const float* haw = ha_w + (size_t)r * 4 * DM * DM;
    const float* hab = ha_b + (size_t)r * 4 * DM;
    const float* saw = sa_w + (size_t)r * 4 * DM * DM;
    const float* sab = sa_b + (size_t)r * 4 * DM;

    // child stage (child_avg lives in Qb until consumed)
    child_avg_kernel<<<dim3(8, BD), 256, 0, stream>>>(Hcur, ph, mask, Qb);
    gemm256_kernel<<<gG, 256, 0, stream>>>(Hcur, Qb, nullptr,
        ct_w + (size_t)r * 2 * DM * DM, ct_b + (size_t)r * DM, mCb, 512, 1);

    // head attention: Q from Hr, K/V from gathered head_repr
    gemm256_kernel<<<gG, 256, 0, stream>>>(Hcur, nullptr, nullptr, haw + 0 * DM * DM, hab + 0 * DM, Qb,   256, 0);
    gemm256_kernel<<<gG, 256, 0, stream>>>(Hcur, nullptr, ph,      haw + 1 * DM * DM, hab + 1 * DM, Kbuf, 256, 0);
    gemm256_kernel<<<gG, 256, 0, stream>>>(Hcur, nullptr, ph,      haw + 2 * DM * DM, hab + 2 * DM, Vbuf, 256, 0);
    attn_kernel<<<dim3(NHD, BD), 128, 0, stream>>>(Qb, Kbuf, Vbuf, nullptr, nullptr, Ob);
    gemm256_kernel<<<gG, 256, 0, stream>>>(Ob, nullptr, nullptr, haw + 3 * DM * DM, hab + 3 * DM, mHb, 256, 0);

    // sibling attention (masked self-attention)
    gemm256_kernel<<<gG, 256, 0, stream>>>(Hcur, nullptr, nullptr, saw + 0 * DM * DM, sab + 0 * DM, Qb,   256, 0);
    gemm256_kernel<<<gG, 256, 0, stream>>>(Hcur, nullptr, nullptr, saw + 1 * DM * DM, sab + 1 * DM, Kbuf, 256, 0);
    gemm256_kernel<<<gG, 256, 0, stream>>>(Hcur, nullptr, nullptr, saw + 2 * DM * DM, sab + 2 * DM, Vbuf, 256, 0);
    attn_kernel<<<dim3(NHD, BD), 128, 0, stream>>>(Qb, Kbuf, Vbuf, ph, mask, Ob);
    gemm256_kernel<<<gG, 256, 0, stream>>>(Ob, nullptr, nullptr, saw + 3 * DM * DM, sab + 3 * DM, mSb, 256, 0);

    // gated fuse + residual + LayerNorm (in-place Hr update)
    fuse_ln_kernel<<<dim3(16, BD), 256, 0, stream>>>(Hcur, mHb, mCb, mSb,
        gate_w + (size_t)r * 4 * DM * DM, gate_b + (size_t)r * DM,
        tr_w   + (size_t)r * 4 * DM * DM, tr_b   + (size_t)r * DM,
        ln_g + (size_t)r * DM, ln_b + (size_t)r * DM, Hcur);
  }

  // final biaffine scorer
  gemm256_kernel<<<gG, 256, 0, stream>>>(Hcur, nullptr, nullptr, ahw, ahb, Qb,   256, 0); // h_head
  gemm256_kernel<<<gG, 256, 0, stream>>>(Hcur, nullptr, nullptr, adw, adb, Kbuf, 256, 0); // h_dep
  rhrd_kernel<<<dim3(BD), 256, 0, stream>>>(Qb, Kbuf, bhw, bhb, bdw, bdb, rh, rd);
  gemm256_kernel<<<gG, 256, 0, stream>>>(Qb, nullptr, nullptr, bil, nullptr, Vbuf, 256, 0); // h_head @ bilinear
  scores_kernel<<<dim3(8, 8, BD), 256, 0, stream>>>(Vbuf, Kbuf, rh, rd, (float*)d_out + AB);

  // Hr output (fp32)
  cvt16to32_kernel<<<dim3(2048), 256, 0, stream>>>(Hcur, (float*)d_out, (int)AB);
}

// Round 3
// 3569.574 us; speedup vs baseline: 2.0786x; 2.0786x over previous
//
#include <hip/hip_runtime.h>
#include <hip/hip_bf16.h>
#include <math.h>

typedef __hip_bfloat16 bf16;
typedef __attribute__((ext_vector_type(8))) short bf16x8v;
typedef __attribute__((ext_vector_type(4))) float f32x4v;

#define BD 256   // batch
#define NN 128   // tokens
#define DM 256   // model dim
#define NHD 4    // heads
#define HDIM 64  // head dim
#define RR 3     // rounds

__device__ __forceinline__ float b2f(bf16 x) { return __bfloat162float(x); }
__device__ __forceinline__ bf16 f2b(float x) { return __float2bfloat16(x); }
__device__ __forceinline__ float geluf(float x) { return 0.5f * x * (1.f + erff(x * 0.70710678118654752f)); }

// fp32 -> bf16 convert
__global__ __launch_bounds__(256) void cvt32to16_kernel(
    const float* __restrict__ in, bf16* __restrict__ out, int n)
{
  int i = blockIdx.x * 256 + threadIdx.x;
  int stride = gridDim.x * 256;
  for (; i < n; i += stride) out[i] = f2b(in[i]);
}

// bf16 -> fp32
__global__ __launch_bounds__(256) void cvt16to32_kernel(
    const bf16* __restrict__ in, float* __restrict__ out, int n)
{
  int i = blockIdx.x * 256 + threadIdx.x;
  int stride = gridDim.x * 256;
  for (; i < n; i += stride) out[i] = b2f(in[i]);
}

// ---------------------------------------------------------------------------
// Batched weight transpose: src fp32 [K][256] row-major -> dst bf16 [256][K].
// Descriptor table: entry e covers tiles [base, base + 8*K/32). 32x32 tiles.
// ---------------------------------------------------------------------------
struct TDesc { const float* src; bf16* dst; int K; int base; };
struct TTable { TDesc e[11]; };

__global__ __launch_bounds__(256) void transpose_w_kernel(TTable T, int nent)
{
  int t = blockIdx.x;
  int ei = 0;
  for (int i = 1; i < nent; i++) if (t >= T.e[i].base) ei = i;
  const float* src = T.e[ei].src;
  bf16* dst = T.e[ei].dst;
  int K = T.e[ei].K;
  int lt = t - T.e[ei].base;
  int nt = lt & 7, kt = lt >> 3;

  __shared__ float tile[32][33];
  int tx = threadIdx.x & 31, ty = threadIdx.x >> 5;
#pragma unroll
  for (int i = 0; i < 4; i++)
    tile[ty + i * 8][tx] = src[(size_t)(kt * 32 + ty + i * 8) * 256 + nt * 32 + tx];
  __syncthreads();
#pragma unroll
  for (int i = 0; i < 4; i++)
    dst[(size_t)(nt * 32 + ty + i * 8) * K + kt * 32 + tx] = f2b(tile[tx][ty + i * 8]);
}

// ---------------------------------------------------------------------------
// MFMA GEMM: out[b,m,c] = act( sum_k A[b,row(m),k] * Wt[c][k] + bias[c] )
// A given as up to 4 concat segments of [B,N,256] bf16 (seg = k>>8).
// Wt: bf16 [256][K] (transposed weights). grid = B, block = 512 (8 waves).
// Wave w: tile rows (w>>2)*64..+64, cols (w&3)*64..+64; 4x4 of 16x16x32 MFMA.
// A-frag: lane l holds A[row = l&15][k = (l>>4)*8 + j]; B-frag same with col.
// C/D: col = lane&15, row = (lane>>4)*4 + reg.
// ---------------------------------------------------------------------------
struct Seg4 { const bf16* p0; const bf16* p1; const bf16* p2; const bf16* p3; };

__global__ __launch_bounds__(512) void gemm_mfma_kernel(
    Seg4 segs, const int* __restrict__ gather, const bf16* __restrict__ Wt,
    const float* __restrict__ bias, bf16* __restrict__ out, int K, int act)
{
  const int b = blockIdx.x;
  const int w = threadIdx.x >> 6;
  const int lane = threadIdx.x & 63;
  const int wr = w >> 2, wc = w & 3;
  const int r16 = lane & 15;
  const int kg = lane >> 4;

  const bf16* sp[4] = { segs.p0, segs.p1, segs.p2, segs.p3 };

  size_t rowoff[4];
#pragma unroll
  for (int mi = 0; mi < 4; mi++) {
    int row = wr * 64 + mi * 16 + r16;
    if (gather) { int g = gather[b * NN + row]; row = min(max(g, 0), NN - 1); }
    rowoff[mi] = ((size_t)b * NN + row) * DM;
  }
  size_t coloff[4];
#pragma unroll
  for (int ni = 0; ni < 4; ni++)
    coloff[ni] = (size_t)(wc * 64 + ni * 16 + r16) * K;

  f32x4v zero = {0.f, 0.f, 0.f, 0.f};
  f32x4v acc[4][4];
#pragma unroll
  for (int mi = 0; mi < 4; mi++)
#pragma unroll
    for (int ni = 0; ni < 4; ni++) acc[mi][ni] = zero;

  for (int k0 = 0; k0 < K; k0 += 32) {
    int k = k0 + kg * 8;
    const bf16* Ab = sp[k >> 8] + (k & 255);
    bf16x8v a[4], bb[4];
#pragma unroll
    for (int mi = 0; mi < 4; mi++)
      a[mi] = *(const bf16x8v*)(Ab + rowoff[mi]);
#pragma unroll
    for (int ni = 0; ni < 4; ni++)
      bb[ni] = *(const bf16x8v*)(Wt + coloff[ni] + k);
#pragma unroll
    for (int mi = 0; mi < 4; mi++)
#pragma unroll
      for (int ni = 0; ni < 4; ni++)
        acc[mi][ni] = __builtin_amdgcn_mfma_f32_16x16x32_bf16(a[mi], bb[ni], acc[mi][ni], 0, 0, 0);
  }

#pragma unroll
  for (int ni = 0; ni < 4; ni++) {
    int col = wc * 64 + ni * 16 + r16;
    float bv = bias ? bias[col] : 0.f;
#pragma unroll
    for (int mi = 0; mi < 4; mi++) {
      int row0 = wr * 64 + mi * 16 + kg * 4;
      size_t base = ((size_t)b * NN + row0) * DM + col;
#pragma unroll
      for (int r = 0; r < 4; r++) {
        float x = acc[mi][ni][r] + bv;
        if (act == 1) x = geluf(x);
        out[base + (size_t)r * DM] = f2b(x);
      }
    }
  }
}

// ---------------------------------------------------------------------------
// scores[b,q,m] = sum_d tmp[b,q,d]*hd[b,m,d] + rh[b,m] + rd[b,q]  (fp32 out)
// grid = B, 8 waves; wave tile 32 (q) x 64 (m): wr=w>>1 (0..3), wc=w&1.
// ---------------------------------------------------------------------------
__global__ __launch_bounds__(512) void scores_mfma_kernel(
    const bf16* __restrict__ tmp, const bf16* __restrict__ hd,
    const float* __restrict__ rh, const float* __restrict__ rd,
    float* __restrict__ out)
{
  const int b = blockIdx.x;
  const int w = threadIdx.x >> 6;
  const int lane = threadIdx.x & 63;
  const int wr = w >> 1, wc = w & 1;
  const int r16 = lane & 15;
  const int kg = lane >> 4;

  size_t qoff[2], moff[4];
#pragma unroll
  for (int mi = 0; mi < 2; mi++) qoff[mi] = ((size_t)b * NN + wr * 32 + mi * 16 + r16) * DM;
#pragma unroll
  for (int ni = 0; ni < 4; ni++) moff[ni] = ((size_t)b * NN + wc * 64 + ni * 16 + r16) * DM;

  f32x4v zero = {0.f, 0.f, 0.f, 0.f};
  f32x4v acc[2][4];
#pragma unroll
  for (int mi = 0; mi < 2; mi++)
#pragma unroll
    for (int ni = 0; ni < 4; ni++) acc[mi][ni] = zero;

  for (int k0 = 0; k0 < DM; k0 += 32) {
    int k = k0 + kg * 8;
    bf16x8v a[2], bb[4];
#pragma unroll
    for (int mi = 0; mi < 2; mi++) a[mi] = *(const bf16x8v*)(tmp + qoff[mi] + k);
#pragma unroll
    for (int ni = 0; ni < 4; ni++) bb[ni] = *(const bf16x8v*)(hd + moff[ni] + k);
#pragma unroll
    for (int mi = 0; mi < 2; mi++)
#pragma unroll
      for (int ni = 0; ni < 4; ni++)
        acc[mi][ni] = __builtin_amdgcn_mfma_f32_16x16x32_bf16(a[mi], bb[ni], acc[mi][ni], 0, 0, 0);
  }

#pragma unroll
  for (int ni = 0; ni < 4; ni++) {
    int m = wc * 64 + ni * 16 + r16;
    float rhm = rh[b * NN + m];
#pragma unroll
    for (int mi = 0; mi < 2; mi++) {
      int q0 = wr * 32 + mi * 16 + kg * 4;
#pragma unroll
      for (int r = 0; r < 4; r++)
        out[(size_t)b * NN * NN + (size_t)(q0 + r) * NN + m] =
            acc[mi][ni][r] + rhm + rd[b * NN + q0 + r];
    }
  }
}

// ---------------------------------------------------------------------------
// Fused attention for one (batch, head) — unchanged from round 2 (verified).
// ---------------------------------------------------------------------------
__global__ __launch_bounds__(128) void attn_kernel(
    const bf16* __restrict__ Qb, const bf16* __restrict__ Kb, const bf16* __restrict__ Vb,
    const int* __restrict__ ph, const float* __restrict__ mask,
    bf16* __restrict__ Ob)
{
  const int b = blockIdx.y, h = blockIdx.x;
  const int t = threadIdx.x;
  __shared__ bf16 Ksh[NN][66];
  __shared__ bf16 Vsh[NN][66];
  __shared__ float q_sh[HDIM];
  __shared__ float p_sh[NN];
  __shared__ float red[2];
  __shared__ float opart[2][HDIM];

  for (int idx = t; idx < NN * HDIM; idx += 128) {
    int row = idx >> 6, d = idx & 63;
    size_t g = ((size_t)b * NN + row) * DM + h * HDIM + d;
    Ksh[row][d] = Kb[g];
    Vsh[row][d] = Vb[g];
  }
  int myph = 0; float mymsk = 1.f;
  if (ph) { myph = ph[(size_t)b * NN + t]; mymsk = mask[(size_t)b * NN + t]; }
  __syncthreads();

  for (int q = 0; q < NN; q++) {
    if (t < HDIM) q_sh[t] = b2f(Qb[((size_t)b * NN + q) * DM + h * HDIM + t]);
    __syncthreads();

    float s = 0.f;
#pragma unroll 8
    for (int d = 0; d < HDIM; d++) s += q_sh[d] * b2f(Ksh[t][d]);
    s *= 0.125f;
    if (ph) {
      int qph = ph[(size_t)b * NN + q];
      float qmsk = mask[(size_t)b * NN + q];
      bool sib = (qph == myph) && (q != t) && (mymsk > 0.f) && (qmsk > 0.f);
      if (!sib) s = -1e9f;
    }
    float mx = s;
#pragma unroll
    for (int o = 1; o < 64; o <<= 1) mx = fmaxf(mx, __shfl_xor(mx, o, 64));
    if ((t & 63) == 0) red[t >> 6] = mx;
    __syncthreads();
    mx = fmaxf(red[0], red[1]);
    float p = __expf(s - mx);
    float sm = p;
#pragma unroll
    for (int o = 1; o < 64; o <<= 1) sm += __shfl_xor(sm, o, 64);
    __syncthreads();
    if ((t & 63) == 0) red[t >> 6] = sm;
    __syncthreads();
    p = p / (red[0] + red[1]);
    p_sh[t] = p;
    __syncthreads();

    int d = t & 63, half = t >> 6;
    float o_ = 0.f;
#pragma unroll 8
    for (int k = 0; k < 64; k++) {
      int kk = half * 64 + k;
      o_ += p_sh[kk] * b2f(Vsh[kk][d]);
    }
    opart[half][d] = o_;
    __syncthreads();
    if (t < HDIM)
      Ob[((size_t)b * NN + q) * DM + h * HDIM + t] = f2b(opart[0][t] + opart[1][t]);
    __syncthreads();
  }
}

// ---------------------------------------------------------------------------
// child_avg — unchanged (verified).
// ---------------------------------------------------------------------------
__global__ __launch_bounds__(256) void child_avg_kernel(
    const bf16* __restrict__ Hr, const int* __restrict__ ph, const float* __restrict__ mask,
    bf16* __restrict__ CA)
{
  const int b = blockIdx.y;
  const int m0 = blockIdx.x * 16;
  const int d = threadIdx.x;
  __shared__ int hi_sh[NN];
  __shared__ float mk_sh[NN];
  if (threadIdx.x < NN) {
    int g = ph[(size_t)b * NN + threadIdx.x];
    hi_sh[threadIdx.x] = min(max(g, 0), NN - 1);
    mk_sh[threadIdx.x] = mask[(size_t)b * NN + threadIdx.x];
  }
  __syncthreads();

  float acc[16], cnt[16];
#pragma unroll
  for (int m = 0; m < 16; m++) { acc[m] = 0.f; cnt[m] = 0.f; }
  for (int n = 0; n < NN; n++) {
    int hn = hi_sh[n];
    float v = b2f(Hr[((size_t)b * NN + n) * DM + d]);
    float mv = mk_sh[n];
#pragma unroll
    for (int m = 0; m < 16; m++) {
      bool hit = (hn == m0 + m);
      acc[m] += hit ? v : 0.f;
      cnt[m] += hit ? mv : 0.f;
    }
  }
#pragma unroll
  for (int m = 0; m < 16; m++) {
    float a = acc[m] / fmaxf(cnt[m], 1.f);
    CA[((size_t)b * NN + m0 + m) * DM + d] = f2b(a);
  }
}

// ---------------------------------------------------------------------------
// LN epilogue: Hn = Hr + sigmoid(Gpre)*gelu(Upre); LayerNorm -> Hout.
// grid (16, B), block 256 (thread = col), 8 rows per block. In-place safe.
// ---------------------------------------------------------------------------
__global__ __launch_bounds__(256) void ln_epi_kernel(
    const bf16* __restrict__ Hr, const bf16* __restrict__ Gp, const bf16* __restrict__ Up,
    const float* __restrict__ lg, const float* __restrict__ lb, bf16* __restrict__ Hout)
{
  const int b = blockIdx.y;
  const int m0 = blockIdx.x * 8;
  const int c = threadIdx.x;
  __shared__ float red[8];
  float lgv = lg[c], lbv = lb[c];
  int wv = c >> 6, ln = c & 63;
  for (int m = 0; m < 8; m++) {
    size_t idx = ((size_t)b * NN + m0 + m) * DM + c;
    float g = 1.f / (1.f + __expf(-b2f(Gp[idx])));
    float u = geluf(b2f(Up[idx]));
    float hn = b2f(Hr[idx]) + g * u;
    float s1 = hn, s2 = hn * hn;
#pragma unroll
    for (int o = 1; o < 64; o <<= 1) { s1 += __shfl_xor(s1, o, 64); s2 += __shfl_xor(s2, o, 64); }
    if (ln == 0) { red[wv] = s1; red[4 + wv] = s2; }
    __syncthreads();
    float sum = red[0] + red[1] + red[2] + red[3];
    float sq  = red[4] + red[5] + red[6] + red[7];
    float mu = sum * (1.f / DM);
    float var = sq * (1.f / DM) - mu * mu;
    float y = (hn - mu) * rsqrtf(var + 1e-5f) * lgv + lbv;
    Hout[idx] = f2b(y);
    __syncthreads();
  }
}

// rh/rd — unchanged (verified).
__global__ __launch_bounds__(256) void rhrd_kernel(
    const bf16* __restrict__ hh, const bf16* __restrict__ hd,
    const float* __restrict__ bhw, const float* __restrict__ bhb,
    const float* __restrict__ bdw, const float* __restrict__ bdb,
    float* __restrict__ rh, float* __restrict__ rd)
{
  int b = blockIdx.x;
  int t = threadIdx.x;
  int n = t & 127;
  bool isD = t >= 128;
  const bf16* row = (isD ? hd : hh) + ((size_t)b * NN + n) * DM;
  const float* wv = isD ? bdw : bhw;
  float s = isD ? bdb[0] : bhb[0];
  for (int k = 0; k < DM; k++) s += b2f(row[k]) * wv[k];
  (isD ? rd : rh)[(size_t)b * NN + n] = s;
}

// ---------------------------------------------------------------------------
extern "C" void kernel_launch(void* const* d_in, const int* in_sizes, int n_in,
                              void* d_out, int out_size, void* d_ws, size_t ws_size,
                              hipStream_t stream) {
  const float* H      = (const float*)d_in[0];
  const int*   ph     = (const int*)  d_in[1];
  const float* mask   = (const float*)d_in[2];
  const float* ha_w   = (const float*)d_in[3];
  const float* ha_b   = (const float*)d_in[4];
  const float* sa_w   = (const float*)d_in[5];
  const float* sa_b   = (const float*)d_in[6];
  const float* ct_w   = (const float*)d_in[7];
  const float* ct_b   = (const float*)d_in[8];
  const float* gate_w = (const float*)d_in[9];
  const float* gate_b = (const float*)d_in[10];
  const float* tr_w   = (const float*)d_in[11];
  const float* tr_b   = (const float*)d_in[12];
  const float* ln_g   = (const float*)d_in[13];
  const float* ln_b   = (const float*)d_in[14];
  const float* ahw    = (const float*)d_in[15];
  const float* ahb    = (const float*)d_in[16];
  const float* adw    = (const float*)d_in[17];
  const float* adb    = (const float*)d_in[18];
  const float* bil    = (const float*)d_in[19];
  const float* bhw    = (const float*)d_in[20];
  const float* bhb    = (const float*)d_in[21];
  const float* bdw    = (const float*)d_in[22];
  const float* bdb    = (const float*)d_in[23];

  const size_t AB = (size_t)BD * NN * DM;  // 8,388,608 elems
  bf16* wsb  = (bf16*)d_ws;
  bf16* Hcur = wsb + 0 * AB;
  bf16* Qb   = wsb + 1 * AB;
  bf16* Kbuf = wsb + 2 * AB;
  bf16* Vbuf = wsb + 3 * AB;
  bf16* Ob   = wsb + 4 * AB;
  bf16* mHb  = wsb + 5 * AB;
  bf16* mSb  = wsb + 6 * AB;
  bf16* wT   = wsb + 7 * AB;          // 1,179,648 bf16 transposed-weight arena
  bf16* haT  = wT;                    // 4 x 65536
  bf16* saT  = wT + 262144;           // 4 x 65536
  bf16* ctT  = wT + 524288;           // 131072
  bf16* gT   = wT + 655360;           // 262144
  bf16* tT   = wT + 917504;           // 262144
  float* rh  = (float*)(wT + 1179648);
  float* rd  = rh + (size_t)BD * NN;

  cvt32to16_kernel<<<dim3(2048), 256, 0, stream>>>(H, Hcur, (int)AB);

  for (int r = 0; r < RR; r++) {
    // ---- transpose this round's weights to bf16 [N][K] ----
    TTable T; int base = 0;
    for (int i = 0; i < 4; i++) {
      T.e[i] = { ha_w + ((size_t)r * 4 + i) * 65536, haT + (size_t)i * 65536, 256, base };
      base += 64;
    }
    for (int i = 0; i < 4; i++) {
      T.e[4 + i] = { sa_w + ((size_t)r * 4 + i) * 65536, saT + (size_t)i * 65536, 256, base };
      base += 64;
    }
    T.e[8]  = { ct_w   + (size_t)r * 131072, ctT, 512,  base }; base += 128;
    T.e[9]  = { gate_w + (size_t)r * 262144, gT,  1024, base }; base += 256;
    T.e[10] = { tr_w   + (size_t)r * 262144, tT,  1024, base }; base += 256;
    transpose_w_kernel<<<dim3(base), 256, 0, stream>>>(T, 11);

    const float* hab = ha_b + (size_t)r * 4 * DM;
    const float* sab = sa_b + (size_t)r * 4 * DM;
    Seg4 sH = { Hcur, Hcur, Hcur, Hcur };
    Seg4 sO = { Ob, Ob, Ob, Ob };

    // ---- head attention ----
    gemm_mfma_kernel<<<dim3(BD), 512, 0, stream>>>(sH, nullptr, haT,          hab + 0,   Qb,   256, 0);
    gemm_mfma_kernel<<<dim3(BD), 512, 0, stream>>>(sH, ph,      haT + 65536,  hab + 256, Kbuf, 256, 0);
    gemm_mfma_kernel<<<dim3(BD), 512, 0, stream>>>(sH, ph,      haT + 131072, hab + 512, Vbuf, 256, 0);
    attn_kernel<<<dim3(NHD, BD), 128, 0, stream>>>(Qb, Kbuf, Vbuf, nullptr, nullptr, Ob);
    gemm_mfma_kernel<<<dim3(BD), 512, 0, stream>>>(sO, nullptr, haT + 196608, hab + 768, mHb, 256, 0);

    // ---- sibling attention ----
    gemm_mfma_kernel<<<dim3(BD), 512, 0, stream>>>(sH, nullptr, saT,          sab + 0,   Qb,   256, 0);
    gemm_mfma_kernel<<<dim3(BD), 512, 0, stream>>>(sH, nullptr, saT + 65536,  sab + 256, Kbuf, 256, 0);
    gemm_mfma_kernel<<<dim3(BD), 512, 0, stream>>>(sH, nullptr, saT + 131072, sab + 512, Vbuf, 256, 0);
    attn_kernel<<<dim3(NHD, BD), 128, 0, stream>>>(Qb, Kbuf, Vbuf, ph, mask, Ob);
    gemm_mfma_kernel<<<dim3(BD), 512, 0, stream>>>(sO, nullptr, saT + 196608, sab + 768, mSb, 256, 0);

    // ---- child message (child_avg -> Qb; gelu GEMM K=512 -> Vbuf) ----
    child_avg_kernel<<<dim3(8, BD), 256, 0, stream>>>(Hcur, ph, mask, Qb);
    Seg4 sC = { Hcur, Qb, Hcur, Hcur };
    gemm_mfma_kernel<<<dim3(BD), 512, 0, stream>>>(sC, nullptr, ctT, ct_b + (size_t)r * DM, Vbuf, 512, 1);

    // ---- gated fuse (K=1024) + LN ----
    Seg4 sF = { Hcur, mHb, Vbuf, mSb };
    gemm_mfma_kernel<<<dim3(BD), 512, 0, stream>>>(sF, nullptr, gT, gate_b + (size_t)r * DM, Kbuf, 1024, 0); // Gpre
    gemm_mfma_kernel<<<dim3(BD), 512, 0, stream>>>(sF, nullptr, tT, tr_b   + (size_t)r * DM, Qb,   1024, 0); // Upre
    ln_epi_kernel<<<dim3(16, BD), 256, 0, stream>>>(Hcur, Kbuf, Qb,
        ln_g + (size_t)r * DM, ln_b + (size_t)r * DM, Hcur);
  }

  // ---- final biaffine scorer ----
  {
    TTable T;
    T.e[0] = { ahw, wT,           256, 0 };
    T.e[1] = { adw, wT + 65536,   256, 64 };
    T.e[2] = { bil, wT + 131072,  256, 128 };
    transpose_w_kernel<<<dim3(192), 256, 0, stream>>>(T, 3);
  }
  Seg4 sH2 = { Hcur, Hcur, Hcur, Hcur };
  gemm_mfma_kernel<<<dim3(BD), 512, 0, stream>>>(sH2, nullptr, wT,          ahb, Qb,   256, 0); // h_head
  gemm_mfma_kernel<<<dim3(BD), 512, 0, stream>>>(sH2, nullptr, wT + 65536,  adb, Kbuf, 256, 0); // h_dep
  rhrd_kernel<<<dim3(BD), 256, 0, stream>>>(Qb, Kbuf, bhw, bhb, bdw, bdb, rh, rd);
  Seg4 sQ = { Qb, Qb, Qb, Qb };
  gemm_mfma_kernel<<<dim3(BD), 512, 0, stream>>>(sQ, nullptr, wT + 131072, nullptr, Vbuf, 256, 0); // h_head @ bilinear
  scores_mfma_kernel<<<dim3(BD), 512, 0, stream>>>(Vbuf, Kbuf, rh, rd, (float*)d_out + AB);

  cvt16to32_kernel<<<dim3(2048), 256, 0, stream>>>(Hcur, (float*)d_out, (int)AB);
}

// Round 4
// 1883.559 us; speedup vs baseline: 3.9392x; 1.8951x over previous
//
#include <hip/hip_runtime.h>
#include <hip/hip_bf16.h>
#include <math.h>

typedef __hip_bfloat16 bf16;
typedef __attribute__((ext_vector_type(8))) short bf16x8v;
typedef __attribute__((ext_vector_type(4))) float f32x4v;

#define BD 256   // batch
#define NN 128   // tokens
#define DM 256   // model dim
#define NHD 4    // heads
#define HDIM 64  // head dim
#define RR 3     // rounds

__device__ __forceinline__ float b2f(bf16 x) { return __bfloat162float(x); }
__device__ __forceinline__ bf16 f2b(float x) { return __float2bfloat16(x); }
__device__ __forceinline__ float geluf(float x) { return 0.5f * x * (1.f + erff(x * 0.70710678118654752f)); }

// fp32 -> bf16 convert
__global__ __launch_bounds__(256) void cvt32to16_kernel(
    const float* __restrict__ in, bf16* __restrict__ out, int n)
{
  int i = blockIdx.x * 256 + threadIdx.x;
  int stride = gridDim.x * 256;
  for (; i < n; i += stride) out[i] = f2b(in[i]);
}

// bf16 -> fp32
__global__ __launch_bounds__(256) void cvt16to32_kernel(
    const bf16* __restrict__ in, float* __restrict__ out, int n)
{
  int i = blockIdx.x * 256 + threadIdx.x;
  int stride = gridDim.x * 256;
  for (; i < n; i += stride) out[i] = b2f(in[i]);
}

// ---------------------------------------------------------------------------
// Batched weight transpose: src fp32 [K][256] row-major -> dst bf16 [256][K].
// ---------------------------------------------------------------------------
struct TDesc { const float* src; bf16* dst; int K; int base; };
struct TTable { TDesc e[11]; };

__global__ __launch_bounds__(256) void transpose_w_kernel(TTable T, int nent)
{
  int t = blockIdx.x;
  int ei = 0;
  for (int i = 1; i < nent; i++) if (t >= T.e[i].base) ei = i;
  const float* src = T.e[ei].src;
  bf16* dst = T.e[ei].dst;
  int K = T.e[ei].K;
  int lt = t - T.e[ei].base;
  int nt = lt & 7, kt = lt >> 3;

  __shared__ float tile[32][33];
  int tx = threadIdx.x & 31, ty = threadIdx.x >> 5;
#pragma unroll
  for (int i = 0; i < 4; i++)
    tile[ty + i * 8][tx] = src[(size_t)(kt * 32 + ty + i * 8) * 256 + nt * 32 + tx];
  __syncthreads();
#pragma unroll
  for (int i = 0; i < 4; i++)
    dst[(size_t)(nt * 32 + ty + i * 8) * K + kt * 32 + tx] = f2b(tile[tx][ty + i * 8]);
}

// ---------------------------------------------------------------------------
// MFMA GEMM: out[b,m,c] = act( sum_k A[b,row(m),k] * Wt[c][k] + bias[c] )
// transp=1: out stored transposed as out[b, c, m]  (for V^T used by attention).
// ---------------------------------------------------------------------------
struct Seg4 { const bf16* p0; const bf16* p1; const bf16* p2; const bf16* p3; };

__global__ __launch_bounds__(512) void gemm_mfma_kernel(
    Seg4 segs, const int* __restrict__ gather, const bf16* __restrict__ Wt,
    const float* __restrict__ bias, bf16* __restrict__ out, int K, int act, int transp)
{
  const int b = blockIdx.x;
  const int w = threadIdx.x >> 6;
  const int lane = threadIdx.x & 63;
  const int wr = w >> 2, wc = w & 3;
  const int r16 = lane & 15;
  const int kg = lane >> 4;

  const bf16* sp[4] = { segs.p0, segs.p1, segs.p2, segs.p3 };

  size_t rowoff[4];
#pragma unroll
  for (int mi = 0; mi < 4; mi++) {
    int row = wr * 64 + mi * 16 + r16;
    if (gather) { int g = gather[b * NN + row]; row = min(max(g, 0), NN - 1); }
    rowoff[mi] = ((size_t)b * NN + row) * DM;
  }
  size_t coloff[4];
#pragma unroll
  for (int ni = 0; ni < 4; ni++)
    coloff[ni] = (size_t)(wc * 64 + ni * 16 + r16) * K;

  f32x4v zero = {0.f, 0.f, 0.f, 0.f};
  f32x4v acc[4][4];
#pragma unroll
  for (int mi = 0; mi < 4; mi++)
#pragma unroll
    for (int ni = 0; ni < 4; ni++) acc[mi][ni] = zero;

  for (int k0 = 0; k0 < K; k0 += 32) {
    int k = k0 + kg * 8;
    const bf16* Ab = sp[k >> 8] + (k & 255);
    bf16x8v a[4], bb[4];
#pragma unroll
    for (int mi = 0; mi < 4; mi++)
      a[mi] = *(const bf16x8v*)(Ab + rowoff[mi]);
#pragma unroll
    for (int ni = 0; ni < 4; ni++)
      bb[ni] = *(const bf16x8v*)(Wt + coloff[ni] + k);
#pragma unroll
    for (int mi = 0; mi < 4; mi++)
#pragma unroll
      for (int ni = 0; ni < 4; ni++)
        acc[mi][ni] = __builtin_amdgcn_mfma_f32_16x16x32_bf16(a[mi], bb[ni], acc[mi][ni], 0, 0, 0);
  }

#pragma unroll
  for (int ni = 0; ni < 4; ni++) {
    int col = wc * 64 + ni * 16 + r16;
    float bv = bias ? bias[col] : 0.f;
#pragma unroll
    for (int mi = 0; mi < 4; mi++) {
      int row0 = wr * 64 + mi * 16 + kg * 4;
      if (!transp) {
        size_t base = ((size_t)b * NN + row0) * DM + col;
#pragma unroll
        for (int r = 0; r < 4; r++) {
          float x = acc[mi][ni][r] + bv;
          if (act == 1) x = geluf(x);
          out[base + (size_t)r * DM] = f2b(x);
        }
      } else {
        size_t base = ((size_t)b * DM + col) * NN + row0;
#pragma unroll
        for (int r = 0; r < 4; r++) {
          float x = acc[mi][ni][r] + bv;
          if (act == 1) x = geluf(x);
          out[base + r] = f2b(x);
        }
      }
    }
  }
}

// ---------------------------------------------------------------------------
// MFMA attention for one (batch, head). Q,K bf16 [B,N,256] (head slice h*64),
// Vt bf16 [B, 256, N] (pre-transposed). ph!=null => sibling mask.
// block 256 = 4 waves; wave w owns q-rows w*32..w*32+31.
// ---------------------------------------------------------------------------
__global__ __launch_bounds__(256) void attn_mfma_kernel(
    const bf16* __restrict__ Qb, const bf16* __restrict__ Kb, const bf16* __restrict__ Vt,
    const int* __restrict__ ph, const float* __restrict__ mask,
    bf16* __restrict__ Ob)
{
  const int b = blockIdx.y, h = blockIdx.x;
  const int w = threadIdx.x >> 6;
  const int lane = threadIdx.x & 63;
  const int r16 = lane & 15, kg = lane >> 4;
  const int q0 = w * 32;

  __shared__ bf16 P_lds[4][32 * 128];   // per-wave P tile, XOR-swizzled
  __shared__ int   ph_sh[NN];
  __shared__ float mk_sh[NN];

  const bool has_mask = (ph != nullptr);
  if (has_mask && threadIdx.x < NN) {
    ph_sh[threadIdx.x] = ph[(size_t)b * NN + threadIdx.x];
    mk_sh[threadIdx.x] = mask[(size_t)b * NN + threadIdx.x];
  }
  __syncthreads();

  const bf16* Qh = Qb + (size_t)b * NN * DM + (size_t)h * HDIM;
  const bf16* Kh = Kb + (size_t)b * NN * DM + (size_t)h * HDIM;
  const bf16* Vh = Vt + ((size_t)b * DM + (size_t)h * HDIM) * NN;

  f32x4v zero = {0.f, 0.f, 0.f, 0.f};

  // ---- S = Q K^T ----
  f32x4v accs[2][8];
#pragma unroll
  for (int mi = 0; mi < 2; mi++)
#pragma unroll
    for (int ni = 0; ni < 8; ni++) accs[mi][ni] = zero;

#pragma unroll
  for (int ks = 0; ks < 2; ks++) {
    int d = ks * 32 + kg * 8;
    bf16x8v a[2], bb[8];
#pragma unroll
    for (int mi = 0; mi < 2; mi++)
      a[mi] = *(const bf16x8v*)(Qh + (size_t)(q0 + mi * 16 + r16) * DM + d);
#pragma unroll
    for (int ni = 0; ni < 8; ni++)
      bb[ni] = *(const bf16x8v*)(Kh + (size_t)(ni * 16 + r16) * DM + d);
#pragma unroll
    for (int mi = 0; mi < 2; mi++)
#pragma unroll
      for (int ni = 0; ni < 8; ni++)
        accs[mi][ni] = __builtin_amdgcn_mfma_f32_16x16x32_bf16(a[mi], bb[ni], accs[mi][ni], 0, 0, 0);
  }

  // ---- softmax (row spread over 16-lane group; reduce via shfl_xor 1..8) ----
#pragma unroll
  for (int mi = 0; mi < 2; mi++) {
#pragma unroll
    for (int r = 0; r < 4; r++) {
      int wq = mi * 16 + kg * 4 + r;       // row within wave tile
      int q_e = q0 + wq;
      float v[8];
      float mx = -3.0e38f;
      int qp = 0; float qm = 1.f;
      if (has_mask) { qp = ph_sh[q_e]; qm = mk_sh[q_e]; }
#pragma unroll
      for (int ni = 0; ni < 8; ni++) {
        float s = accs[mi][ni][r] * 0.125f;
        if (has_mask) {
          int t_e = ni * 16 + r16;
          bool sib = (qp == ph_sh[t_e]) && (q_e != t_e) && (qm > 0.f) && (mk_sh[t_e] > 0.f);
          if (!sib) s = -1e9f;
        }
        v[ni] = s;
        mx = fmaxf(mx, s);
      }
#pragma unroll
      for (int o = 1; o < 16; o <<= 1) mx = fmaxf(mx, __shfl_xor(mx, o, 64));
      float sum = 0.f;
#pragma unroll
      for (int ni = 0; ni < 8; ni++) { v[ni] = __expf(v[ni] - mx); sum += v[ni]; }
#pragma unroll
      for (int o = 1; o < 16; o <<= 1) sum += __shfl_xor(sum, o, 64);
      float inv = 1.f / sum;
      int swz = (wq & 7) << 3;
#pragma unroll
      for (int ni = 0; ni < 8; ni++) {
        int t_e = ni * 16 + r16;
        P_lds[w][(wq * 128 + t_e) ^ swz] = f2b(v[ni] * inv);
      }
    }
  }
  __syncthreads();   // order P writes before reads (also uniform barrier)

  // ---- O = P V ----
  f32x4v acco[2][4];
#pragma unroll
  for (int mi = 0; mi < 2; mi++)
#pragma unroll
    for (int ni = 0; ni < 4; ni++) acco[mi][ni] = zero;

#pragma unroll
  for (int kt = 0; kt < 4; kt++) {
    int t = kt * 32 + kg * 8;
    bf16x8v a[2], bb[4];
#pragma unroll
    for (int mi = 0; mi < 2; mi++) {
      int wqr = mi * 16 + r16;
      int idx = (wqr * 128 + t) ^ ((wqr & 7) << 3);
      a[mi] = *(const bf16x8v*)&P_lds[w][idx];
    }
#pragma unroll
    for (int ni = 0; ni < 4; ni++)
      bb[ni] = *(const bf16x8v*)(Vh + (size_t)(ni * 16 + r16) * NN + t);
#pragma unroll
    for (int mi = 0; mi < 2; mi++)
#pragma unroll
      for (int ni = 0; ni < 4; ni++)
        acco[mi][ni] = __builtin_amdgcn_mfma_f32_16x16x32_bf16(a[mi], bb[ni], acco[mi][ni], 0, 0, 0);
  }

#pragma unroll
  for (int ni = 0; ni < 4; ni++) {
    int d = ni * 16 + r16;
#pragma unroll
    for (int mi = 0; mi < 2; mi++) {
      int qrow = q0 + mi * 16 + kg * 4;
      size_t base = ((size_t)b * NN + qrow) * DM + (size_t)h * HDIM + d;
#pragma unroll
      for (int r = 0; r < 4; r++)
        Ob[base + (size_t)r * DM] = f2b(acco[mi][ni][r]);
    }
  }
}

// ---------------------------------------------------------------------------
// scores[b,q,m] = sum_d tmp[b,q,d]*hd[b,m,d] + rh[b,m] + rd[b,q]  (fp32 out)
// ---------------------------------------------------------------------------
__global__ __launch_bounds__(512) void scores_mfma_kernel(
    const bf16* __restrict__ tmp, const bf16* __restrict__ hd,
    const float* __restrict__ rh, const float* __restrict__ rd,
    float* __restrict__ out)
{
  const int b = blockIdx.x;
  const int w = threadIdx.x >> 6;
  const int lane = threadIdx.x & 63;
  const int wr = w >> 1, wc = w & 1;
  const int r16 = lane & 15;
  const int kg = lane >> 4;

  size_t qoff[2], moff[4];
#pragma unroll
  for (int mi = 0; mi < 2; mi++) qoff[mi] = ((size_t)b * NN + wr * 32 + mi * 16 + r16) * DM;
#pragma unroll
  for (int ni = 0; ni < 4; ni++) moff[ni] = ((size_t)b * NN + wc * 64 + ni * 16 + r16) * DM;

  f32x4v zero = {0.f, 0.f, 0.f, 0.f};
  f32x4v acc[2][4];
#pragma unroll
  for (int mi = 0; mi < 2; mi++)
#pragma unroll
    for (int ni = 0; ni < 4; ni++) acc[mi][ni] = zero;

  for (int k0 = 0; k0 < DM; k0 += 32) {
    int k = k0 + kg * 8;
    bf16x8v a[2], bb[4];
#pragma unroll
    for (int mi = 0; mi < 2; mi++) a[mi] = *(const bf16x8v*)(tmp + qoff[mi] + k);
#pragma unroll
    for (int ni = 0; ni < 4; ni++) bb[ni] = *(const bf16x8v*)(hd + moff[ni] + k);
#pragma unroll
    for (int mi = 0; mi < 2; mi++)
#pragma unroll
      for (int ni = 0; ni < 4; ni++)
        acc[mi][ni] = __builtin_amdgcn_mfma_f32_16x16x32_bf16(a[mi], bb[ni], acc[mi][ni], 0, 0, 0);
  }

#pragma unroll
  for (int ni = 0; ni < 4; ni++) {
    int m = wc * 64 + ni * 16 + r16;
    float rhm = rh[b * NN + m];
#pragma unroll
    for (int mi = 0; mi < 2; mi++) {
      int q0 = wr * 32 + mi * 16 + kg * 4;
#pragma unroll
      for (int r = 0; r < 4; r++)
        out[(size_t)b * NN * NN + (size_t)(q0 + r) * NN + m] =
            acc[mi][ni][r] + rhm + rd[b * NN + q0 + r];
    }
  }
}

// ---------------------------------------------------------------------------
// child_avg — unchanged (verified).
// ---------------------------------------------------------------------------
__global__ __launch_bounds__(256) void child_avg_kernel(
    const bf16* __restrict__ Hr, const int* __restrict__ ph, const float* __restrict__ mask,
    bf16* __restrict__ CA)
{
  const int b = blockIdx.y;
  const int m0 = blockIdx.x * 16;
  const int d = threadIdx.x;
  __shared__ int hi_sh[NN];
  __shared__ float mk_sh[NN];
  if (threadIdx.x < NN) {
    int g = ph[(size_t)b * NN + threadIdx.x];
    hi_sh[threadIdx.x] = min(max(g, 0), NN - 1);
    mk_sh[threadIdx.x] = mask[(size_t)b * NN + threadIdx.x];
  }
  __syncthreads();

  float acc[16], cnt[16];
#pragma unroll
  for (int m = 0; m < 16; m++) { acc[m] = 0.f; cnt[m] = 0.f; }
  for (int n = 0; n < NN; n++) {
    int hn = hi_sh[n];
    float v = b2f(Hr[((size_t)b * NN + n) * DM + d]);
    float mv = mk_sh[n];
#pragma unroll
    for (int m = 0; m < 16; m++) {
      bool hit = (hn == m0 + m);
      acc[m] += hit ? v : 0.f;
      cnt[m] += hit ? mv : 0.f;
    }
  }
#pragma unroll
  for (int m = 0; m < 16; m++) {
    float a = acc[m] / fmaxf(cnt[m], 1.f);
    CA[((size_t)b * NN + m0 + m) * DM + d] = f2b(a);
  }
}

// ---------------------------------------------------------------------------
// LN epilogue — unchanged (verified).
// ---------------------------------------------------------------------------
__global__ __launch_bounds__(256) void ln_epi_kernel(
    const bf16* __restrict__ Hr, const bf16* __restrict__ Gp, const bf16* __restrict__ Up,
    const float* __restrict__ lg, const float* __restrict__ lb, bf16* __restrict__ Hout)
{
  const int b = blockIdx.y;
  const int m0 = blockIdx.x * 8;
  const int c = threadIdx.x;
  __shared__ float red[8];
  float lgv = lg[c], lbv = lb[c];
  int wv = c >> 6, ln = c & 63;
  for (int m = 0; m < 8; m++) {
    size_t idx = ((size_t)b * NN + m0 + m) * DM + c;
    float g = 1.f / (1.f + __expf(-b2f(Gp[idx])));
    float u = geluf(b2f(Up[idx]));
    float hn = b2f(Hr[idx]) + g * u;
    float s1 = hn, s2 = hn * hn;
#pragma unroll
    for (int o = 1; o < 64; o <<= 1) { s1 += __shfl_xor(s1, o, 64); s2 += __shfl_xor(s2, o, 64); }
    if (ln == 0) { red[wv] = s1; red[4 + wv] = s2; }
    __syncthreads();
    float sum = red[0] + red[1] + red[2] + red[3];
    float sq  = red[4] + red[5] + red[6] + red[7];
    float mu = sum * (1.f / DM);
    float var = sq * (1.f / DM) - mu * mu;
    float y = (hn - mu) * rsqrtf(var + 1e-5f) * lgv + lbv;
    Hout[idx] = f2b(y);
    __syncthreads();
  }
}

// rh/rd — unchanged (verified).
__global__ __launch_bounds__(256) void rhrd_kernel(
    const bf16* __restrict__ hh, const bf16* __restrict__ hd,
    const float* __restrict__ bhw, const float* __restrict__ bhb,
    const float* __restrict__ bdw, const float* __restrict__ bdb,
    float* __restrict__ rh, float* __restrict__ rd)
{
  int b = blockIdx.x;
  int t = threadIdx.x;
  int n = t & 127;
  bool isD = t >= 128;
  const bf16* row = (isD ? hd : hh) + ((size_t)b * NN + n) * DM;
  const float* wv = isD ? bdw : bhw;
  float s = isD ? bdb[0] : bhb[0];
  for (int k = 0; k < DM; k++) s += b2f(row[k]) * wv[k];
  (isD ? rd : rh)[(size_t)b * NN + n] = s;
}

// ---------------------------------------------------------------------------
extern "C" void kernel_launch(void* const* d_in, const int* in_sizes, int n_in,
                              void* d_out, int out_size, void* d_ws, size_t ws_size,
                              hipStream_t stream) {
  const float* H      = (const float*)d_in[0];
  const int*   ph     = (const int*)  d_in[1];
  const float* mask   = (const float*)d_in[2];
  const float* ha_w   = (const float*)d_in[3];
  const float* ha_b   = (const float*)d_in[4];
  const float* sa_w   = (const float*)d_in[5];
  const float* sa_b   = (const float*)d_in[6];
  const float* ct_w   = (const float*)d_in[7];
  const float* ct_b   = (const float*)d_in[8];
  const float* gate_w = (const float*)d_in[9];
  const float* gate_b = (const float*)d_in[10];
  const float* tr_w   = (const float*)d_in[11];
  const float* tr_b   = (const float*)d_in[12];
  const float* ln_g   = (const float*)d_in[13];
  const float* ln_b   = (const float*)d_in[14];
  const float* ahw    = (const float*)d_in[15];
  const float* ahb    = (const float*)d_in[16];
  const float* adw    = (const float*)d_in[17];
  const float* adb    = (const float*)d_in[18];
  const float* bil    = (const float*)d_in[19];
  const float* bhw    = (const float*)d_in[20];
  const float* bhb    = (const float*)d_in[21];
  const float* bdw    = (const float*)d_in[22];
  const float* bdb    = (const float*)d_in[23];

  const size_t AB = (size_t)BD * NN * DM;  // 8,388,608 elems
  bf16* wsb  = (bf16*)d_ws;
  bf16* Hcur = wsb + 0 * AB;
  bf16* Qb   = wsb + 1 * AB;
  bf16* Kbuf = wsb + 2 * AB;
  bf16* Vbuf = wsb + 3 * AB;   // V^T [B][DM][NN] during attention; normal layout otherwise
  bf16* Ob   = wsb + 4 * AB;
  bf16* mHb  = wsb + 5 * AB;
  bf16* mSb  = wsb + 6 * AB;
  bf16* wT   = wsb + 7 * AB;          // transposed-weight arena
  bf16* haT  = wT;                    // 4 x 65536
  bf16* saT  = wT + 262144;           // 4 x 65536
  bf16* ctT  = wT + 524288;           // 131072
  bf16* gT   = wT + 655360;           // 262144
  bf16* tT   = wT + 917504;           // 262144
  float* rh  = (float*)(wT + 1179648);
  float* rd  = rh + (size_t)BD * NN;

  cvt32to16_kernel<<<dim3(2048), 256, 0, stream>>>(H, Hcur, (int)AB);

  for (int r = 0; r < RR; r++) {
    // ---- transpose this round's weights to bf16 [N][K] ----
    TTable T; int base = 0;
    for (int i = 0; i < 4; i++) {
      T.e[i] = { ha_w + ((size_t)r * 4 + i) * 65536, haT + (size_t)i * 65536, 256, base };
      base += 64;
    }
    for (int i = 0; i < 4; i++) {
      T.e[4 + i] = { sa_w + ((size_t)r * 4 + i) * 65536, saT + (size_t)i * 65536, 256, base };
      base += 64;
    }
    T.e[8]  = { ct_w   + (size_t)r * 131072, ctT, 512,  base }; base += 128;
    T.e[9]  = { gate_w + (size_t)r * 262144, gT,  1024, base }; base += 256;
    T.e[10] = { tr_w   + (size_t)r * 262144, tT,  1024, base }; base += 256;
    transpose_w_kernel<<<dim3(base), 256, 0, stream>>>(T, 11);

    const float* hab = ha_b + (size_t)r * 4 * DM;
    const float* sab = sa_b + (size_t)r * 4 * DM;
    Seg4 sH = { Hcur, Hcur, Hcur, Hcur };
    Seg4 sO = { Ob, Ob, Ob, Ob };

    // ---- head attention (K/V gathered; V written transposed) ----
    gemm_mfma_kernel<<<dim3(BD), 512, 0, stream>>>(sH, nullptr, haT,          hab + 0,   Qb,   256, 0, 0);
    gemm_mfma_kernel<<<dim3(BD), 512, 0, stream>>>(sH, ph,      haT + 65536,  hab + 256, Kbuf, 256, 0, 0);
    gemm_mfma_kernel<<<dim3(BD), 512, 0, stream>>>(sH, ph,      haT + 131072, hab + 512, Vbuf, 256, 0, 1);
    attn_mfma_kernel<<<dim3(NHD, BD), 256, 0, stream>>>(Qb, Kbuf, Vbuf, nullptr, nullptr, Ob);
    gemm_mfma_kernel<<<dim3(BD), 512, 0, stream>>>(sO, nullptr, haT + 196608, hab + 768, mHb, 256, 0, 0);

    // ---- sibling attention ----
    gemm_mfma_kernel<<<dim3(BD), 512, 0, stream>>>(sH, nullptr, saT,          sab + 0,   Qb,   256, 0, 0);
    gemm_mfma_kernel<<<dim3(BD), 512, 0, stream>>>(sH, nullptr, saT + 65536,  sab + 256, Kbuf, 256, 0, 0);
    gemm_mfma_kernel<<<dim3(BD), 512, 0, stream>>>(sH, nullptr, saT + 131072, sab + 512, Vbuf, 256, 0, 1);
    attn_mfma_kernel<<<dim3(NHD, BD), 256, 0, stream>>>(Qb, Kbuf, Vbuf, ph, mask, Ob);
    gemm_mfma_kernel<<<dim3(BD), 512, 0, stream>>>(sO, nullptr, saT + 196608, sab + 768, mSb, 256, 0, 0);

    // ---- child message (child_avg -> Qb; gelu GEMM K=512 -> Vbuf) ----
    child_avg_kernel<<<dim3(8, BD), 256, 0, stream>>>(Hcur, ph, mask, Qb);
    Seg4 sC = { Hcur, Qb, Hcur, Hcur };
    gemm_mfma_kernel<<<dim3(BD), 512, 0, stream>>>(sC, nullptr, ctT, ct_b + (size_t)r * DM, Vbuf, 512, 1, 0);

    // ---- gated fuse (K=1024) + LN ----
    Seg4 sF = { Hcur, mHb, Vbuf, mSb };
    gemm_mfma_kernel<<<dim3(BD), 512, 0, stream>>>(sF, nullptr, gT, gate_b + (size_t)r * DM, Kbuf, 1024, 0, 0); // Gpre
    gemm_mfma_kernel<<<dim3(BD), 512, 0, stream>>>(sF, nullptr, tT, tr_b   + (size_t)r * DM, Qb,   1024, 0, 0); // Upre
    ln_epi_kernel<<<dim3(16, BD), 256, 0, stream>>>(Hcur, Kbuf, Qb,
        ln_g + (size_t)r * DM, ln_b + (size_t)r * DM, Hcur);
  }

  // ---- final biaffine scorer ----
  {
    TTable T;
    T.e[0] = { ahw, wT,           256, 0 };
    T.e[1] = { adw, wT + 65536,   256, 64 };
    T.e[2] = { bil, wT + 131072,  256, 128 };
    transpose_w_kernel<<<dim3(192), 256, 0, stream>>>(T, 3);
  }
  Seg4 sH2 = { Hcur, Hcur, Hcur, Hcur };
  gemm_mfma_kernel<<<dim3(BD), 512, 0, stream>>>(sH2, nullptr, wT,          ahb, Qb,   256, 0, 0); // h_head
  gemm_mfma_kernel<<<dim3(BD), 512, 0, stream>>>(sH2, nullptr, wT + 65536,  adb, Kbuf, 256, 0, 0); // h_dep
  rhrd_kernel<<<dim3(BD), 256, 0, stream>>>(Qb, Kbuf, bhw, bhb, bdw, bdb, rh, rd);
  Seg4 sQ = { Qb, Qb, Qb, Qb };
  gemm_mfma_kernel<<<dim3(BD), 512, 0, stream>>>(sQ, nullptr, wT + 131072, nullptr, Vbuf, 256, 0, 0); // h_head @ bilinear
  scores_mfma_kernel<<<dim3(BD), 512, 0, stream>>>(Vbuf, Kbuf, rh, rd, (float*)d_out + AB);

  cvt16to32_kernel<<<dim3(2048), 256, 0, stream>>>(Hcur, (float*)d_out, (int)AB);
}

// Round 5
// 1512.577 us; speedup vs baseline: 4.9053x; 1.2453x over previous
//
#include <hip/hip_runtime.h>
#include <hip/hip_bf16.h>
#include <math.h>

typedef __hip_bfloat16 bf16;
typedef __attribute__((ext_vector_type(8))) short bf16x8v;
typedef __attribute__((ext_vector_type(4))) float f32x4v;

#define BD 256   // batch
#define NN 128   // tokens
#define DM 256   // model dim
#define NHD 4    // heads
#define HDIM 64  // head dim
#define RR 3     // rounds

__device__ __forceinline__ float b2f(bf16 x) { return __bfloat162float(x); }
__device__ __forceinline__ bf16 f2b(float x) { return __float2bfloat16(x); }
__device__ __forceinline__ float geluf(float x) { return 0.5f * x * (1.f + erff(x * 0.70710678118654752f)); }

// fp32 -> bf16 convert
__global__ __launch_bounds__(256) void cvt32to16_kernel(
    const float* __restrict__ in, bf16* __restrict__ out, int n)
{
  int i = blockIdx.x * 256 + threadIdx.x;
  int stride = gridDim.x * 256;
  for (; i < n; i += stride) out[i] = f2b(in[i]);
}

// bf16 -> fp32
__global__ __launch_bounds__(256) void cvt16to32_kernel(
    const bf16* __restrict__ in, float* __restrict__ out, int n)
{
  int i = blockIdx.x * 256 + threadIdx.x;
  int stride = gridDim.x * 256;
  for (; i < n; i += stride) out[i] = b2f(in[i]);
}

// ---------------------------------------------------------------------------
// Batched weight transpose: src fp32 [K][256] row-major -> dst bf16 [256][K].
// ---------------------------------------------------------------------------
struct TDesc { const float* src; bf16* dst; int K; int base; };
struct TTable { TDesc e[11]; };

__global__ __launch_bounds__(256) void transpose_w_kernel(TTable T, int nent)
{
  int t = blockIdx.x;
  int ei = 0;
  for (int i = 1; i < nent; i++) if (t >= T.e[i].base) ei = i;
  const float* src = T.e[ei].src;
  bf16* dst = T.e[ei].dst;
  int K = T.e[ei].K;
  int lt = t - T.e[ei].base;
  int nt = lt & 7, kt = lt >> 3;

  __shared__ float tile[32][33];
  int tx = threadIdx.x & 31, ty = threadIdx.x >> 5;
#pragma unroll
  for (int i = 0; i < 4; i++)
    tile[ty + i * 8][tx] = src[(size_t)(kt * 32 + ty + i * 8) * 256 + nt * 32 + tx];
  __syncthreads();
#pragma unroll
  for (int i = 0; i < 4; i++)
    dst[(size_t)(nt * 32 + ty + i * 8) * K + kt * 32 + tx] = f2b(tile[tx][ty + i * 8]);
}

// ---------------------------------------------------------------------------
// Multi-job MFMA GEMM: job selected by blockIdx.y.
// out[b,m,c] = act( sum_k A[b,row(m),k] * Wt[c][k] + bias[c] )
// transp=1: out[b,c,m] (for V^T used by attention).
// ---------------------------------------------------------------------------
struct GJob {
  const bf16 *a0, *a1, *a2, *a3;   // K/256 segments of A
  const int* gather;
  const bf16* Wt;
  const float* bias;
  bf16* out;
  int K, act, transp;
};
struct GJobs8 { GJob j[8]; };

__global__ __launch_bounds__(512) void gemm_multi_kernel(GJobs8 J)
{
  const GJob jb = J.j[blockIdx.y];
  const int b = blockIdx.x;
  const int w = threadIdx.x >> 6;
  const int lane = threadIdx.x & 63;
  const int wr = w >> 2, wc = w & 3;
  const int r16 = lane & 15;
  const int kg = lane >> 4;
  const int K = jb.K;

  const bf16* sp[4] = { jb.a0, jb.a1, jb.a2, jb.a3 };

  size_t rowoff[4];
#pragma unroll
  for (int mi = 0; mi < 4; mi++) {
    int row = wr * 64 + mi * 16 + r16;
    if (jb.gather) { int g = jb.gather[b * NN + row]; row = min(max(g, 0), NN - 1); }
    rowoff[mi] = ((size_t)b * NN + row) * DM;
  }
  size_t coloff[4];
#pragma unroll
  for (int ni = 0; ni < 4; ni++)
    coloff[ni] = (size_t)(wc * 64 + ni * 16 + r16) * K;

  f32x4v zero = {0.f, 0.f, 0.f, 0.f};
  f32x4v acc[4][4];
#pragma unroll
  for (int mi = 0; mi < 4; mi++)
#pragma unroll
    for (int ni = 0; ni < 4; ni++) acc[mi][ni] = zero;

  for (int k0 = 0; k0 < K; k0 += 32) {
    int k = k0 + kg * 8;
    const bf16* Ab = sp[k >> 8] + (k & 255);
    bf16x8v a[4], bb[4];
#pragma unroll
    for (int mi = 0; mi < 4; mi++)
      a[mi] = *(const bf16x8v*)(Ab + rowoff[mi]);
#pragma unroll
    for (int ni = 0; ni < 4; ni++)
      bb[ni] = *(const bf16x8v*)(jb.Wt + coloff[ni] + k);
#pragma unroll
    for (int mi = 0; mi < 4; mi++)
#pragma unroll
      for (int ni = 0; ni < 4; ni++)
        acc[mi][ni] = __builtin_amdgcn_mfma_f32_16x16x32_bf16(a[mi], bb[ni], acc[mi][ni], 0, 0, 0);
  }

#pragma unroll
  for (int ni = 0; ni < 4; ni++) {
    int col = wc * 64 + ni * 16 + r16;
    float bv = jb.bias ? jb.bias[col] : 0.f;
#pragma unroll
    for (int mi = 0; mi < 4; mi++) {
      int row0 = wr * 64 + mi * 16 + kg * 4;
      if (!jb.transp) {
        size_t base = ((size_t)b * NN + row0) * DM + col;
#pragma unroll
        for (int r = 0; r < 4; r++) {
          float x = acc[mi][ni][r] + bv;
          if (jb.act == 1) x = geluf(x);
          jb.out[base + (size_t)r * DM] = f2b(x);
        }
      } else {
        size_t base = ((size_t)b * DM + col) * NN + row0;
#pragma unroll
        for (int r = 0; r < 4; r++) {
          float x = acc[mi][ni][r] + bv;
          if (jb.act == 1) x = geluf(x);
          jb.out[base + r] = f2b(x);
        }
      }
    }
  }
}

// ---------------------------------------------------------------------------
// Fused dual MFMA attention. blockIdx.z: 0 = head-attn (no mask), 1 = sibling.
// Q,K bf16 [B,N,256] (head slice h*64), V bf16 [B,256,N] pre-transposed.
// block 256 = 4 waves; wave w owns q-rows w*32..w*32+31.
// ---------------------------------------------------------------------------
struct AttnArgs {
  const bf16 *Qa, *Ka, *Va; bf16* Oa;
  const bf16 *Qs, *Ks, *Vs; bf16* Os;
};

__global__ __launch_bounds__(256) void attn2_kernel(
    AttnArgs A, const int* __restrict__ ph, const float* __restrict__ mask)
{
  const int b = blockIdx.y, h = blockIdx.x;
  const bool has_mask = (blockIdx.z == 1);
  const bf16* Qb = has_mask ? A.Qs : A.Qa;
  const bf16* Kb = has_mask ? A.Ks : A.Ka;
  const bf16* Vt = has_mask ? A.Vs : A.Va;
  bf16* Ob       = has_mask ? A.Os : A.Oa;

  const int w = threadIdx.x >> 6;
  const int lane = threadIdx.x & 63;
  const int r16 = lane & 15, kg = lane >> 4;
  const int q0 = w * 32;

  __shared__ bf16 P_lds[4][32 * 128];   // per-wave P tile, XOR-swizzled
  __shared__ int   ph_sh[NN];
  __shared__ float mk_sh[NN];

  if (has_mask && threadIdx.x < NN) {
    ph_sh[threadIdx.x] = ph[(size_t)b * NN + threadIdx.x];
    mk_sh[threadIdx.x] = mask[(size_t)b * NN + threadIdx.x];
  }
  __syncthreads();

  const bf16* Qh = Qb + (size_t)b * NN * DM + (size_t)h * HDIM;
  const bf16* Kh = Kb + (size_t)b * NN * DM + (size_t)h * HDIM;
  const bf16* Vh = Vt + ((size_t)b * DM + (size_t)h * HDIM) * NN;

  f32x4v zero = {0.f, 0.f, 0.f, 0.f};

  // ---- S = Q K^T ----
  f32x4v accs[2][8];
#pragma unroll
  for (int mi = 0; mi < 2; mi++)
#pragma unroll
    for (int ni = 0; ni < 8; ni++) accs[mi][ni] = zero;

#pragma unroll
  for (int ks = 0; ks < 2; ks++) {
    int d = ks * 32 + kg * 8;
    bf16x8v a[2], bb[8];
#pragma unroll
    for (int mi = 0; mi < 2; mi++)
      a[mi] = *(const bf16x8v*)(Qh + (size_t)(q0 + mi * 16 + r16) * DM + d);
#pragma unroll
    for (int ni = 0; ni < 8; ni++)
      bb[ni] = *(const bf16x8v*)(Kh + (size_t)(ni * 16 + r16) * DM + d);
#pragma unroll
    for (int mi = 0; mi < 2; mi++)
#pragma unroll
      for (int ni = 0; ni < 8; ni++)
        accs[mi][ni] = __builtin_amdgcn_mfma_f32_16x16x32_bf16(a[mi], bb[ni], accs[mi][ni], 0, 0, 0);
  }

  // ---- softmax (row spread over 16-lane group) ----
#pragma unroll
  for (int mi = 0; mi < 2; mi++) {
#pragma unroll
    for (int r = 0; r < 4; r++) {
      int wq = mi * 16 + kg * 4 + r;
      int q_e = q0 + wq;
      float v[8];
      float mx = -3.0e38f;
      int qp = 0; float qm = 1.f;
      if (has_mask) { qp = ph_sh[q_e]; qm = mk_sh[q_e]; }
#pragma unroll
      for (int ni = 0; ni < 8; ni++) {
        float s = accs[mi][ni][r] * 0.125f;
        if (has_mask) {
          int t_e = ni * 16 + r16;
          bool sib = (qp == ph_sh[t_e]) && (q_e != t_e) && (qm > 0.f) && (mk_sh[t_e] > 0.f);
          if (!sib) s = -1e9f;
        }
        v[ni] = s;
        mx = fmaxf(mx, s);
      }
#pragma unroll
      for (int o = 1; o < 16; o <<= 1) mx = fmaxf(mx, __shfl_xor(mx, o, 64));
      float sum = 0.f;
#pragma unroll
      for (int ni = 0; ni < 8; ni++) { v[ni] = __expf(v[ni] - mx); sum += v[ni]; }
#pragma unroll
      for (int o = 1; o < 16; o <<= 1) sum += __shfl_xor(sum, o, 64);
      float inv = 1.f / sum;
      int swz = (wq & 7) << 3;
#pragma unroll
      for (int ni = 0; ni < 8; ni++) {
        int t_e = ni * 16 + r16;
        P_lds[w][(wq * 128 + t_e) ^ swz] = f2b(v[ni] * inv);
      }
    }
  }
  __syncthreads();

  // ---- O = P V ----
  f32x4v acco[2][4];
#pragma unroll
  for (int mi = 0; mi < 2; mi++)
#pragma unroll
    for (int ni = 0; ni < 4; ni++) acco[mi][ni] = zero;

#pragma unroll
  for (int kt = 0; kt < 4; kt++) {
    int t = kt * 32 + kg * 8;
    bf16x8v a[2], bb[4];
#pragma unroll
    for (int mi = 0; mi < 2; mi++) {
      int wqr = mi * 16 + r16;
      int idx = (wqr * 128 + t) ^ ((wqr & 7) << 3);
      a[mi] = *(const bf16x8v*)&P_lds[w][idx];
    }
#pragma unroll
    for (int ni = 0; ni < 4; ni++)
      bb[ni] = *(const bf16x8v*)(Vh + (size_t)(ni * 16 + r16) * NN + t);
#pragma unroll
    for (int mi = 0; mi < 2; mi++)
#pragma unroll
      for (int ni = 0; ni < 4; ni++)
        acco[mi][ni] = __builtin_amdgcn_mfma_f32_16x16x32_bf16(a[mi], bb[ni], acco[mi][ni], 0, 0, 0);
  }

#pragma unroll
  for (int ni = 0; ni < 4; ni++) {
    int d = ni * 16 + r16;
#pragma unroll
    for (int mi = 0; mi < 2; mi++) {
      int qrow = q0 + mi * 16 + kg * 4;
      size_t base = ((size_t)b * NN + qrow) * DM + (size_t)h * HDIM + d;
#pragma unroll
      for (int r = 0; r < 4; r++)
        Ob[base + (size_t)r * DM] = f2b(acco[mi][ni][r]);
    }
  }
}

// ---------------------------------------------------------------------------
// child_avg v2: one block per batch. Deterministic stable counting sort of
// children (n sorted by head m, then by n), then one pass over Hr rows.
// ---------------------------------------------------------------------------
__global__ __launch_bounds__(256) void child_avg2_kernel(
    const bf16* __restrict__ Hr, const int* __restrict__ ph,
    const float* __restrict__ mask, bf16* __restrict__ CA)
{
  const int b = blockIdx.x;
  const int t = threadIdx.x;
  __shared__ int hi[NN];
  __shared__ float mk[NN];
  __shared__ int cnt[NN], off[NN], rnk[NN], lst[NN];
  __shared__ float cntf[NN];

  if (t < NN) {
    int g = ph[(size_t)b * NN + t];
    hi[t] = min(max(g, 0), NN - 1);
    mk[t] = mask[(size_t)b * NN + t];
  }
  __syncthreads();
  if (t < NN) {
    int c = 0, r = 0; float cf = 0.f;
    int me = hi[t];
    for (int j = 0; j < NN; j++) {
      int hj = hi[j];
      c  += (hj == t);
      cf += (hj == t) ? mk[j] : 0.f;
      r  += (j < t) && (hj == me);
    }
    cnt[t] = c; cntf[t] = cf; rnk[t] = r;
  }
  __syncthreads();
  if (t < NN) {
    int o = 0;
    for (int m = 0; m < t; m++) o += cnt[m];
    off[t] = o;
  }
  __syncthreads();
  if (t < NN) lst[off[hi[t]] + rnk[t]] = t;
  __syncthreads();

  const bf16* Hb = Hr + (size_t)b * NN * DM;
  bf16* Cb = CA + (size_t)b * NN * DM;
  const int d = t;   // 256 threads = 256 columns
  for (int m = 0; m < NN; m++) {
    float s = 0.f;
    int o = off[m], c = cnt[m];
    for (int i = 0; i < c; i++)
      s += b2f(Hb[(size_t)lst[o + i] * DM + d]);
    Cb[(size_t)m * DM + d] = f2b(s / fmaxf(cntf[m], 1.f));
  }
}

// ---------------------------------------------------------------------------
// LN epilogue — unchanged (verified).
// ---------------------------------------------------------------------------
__global__ __launch_bounds__(256) void ln_epi_kernel(
    const bf16* __restrict__ Hr, const bf16* __restrict__ Gp, const bf16* __restrict__ Up,
    const float* __restrict__ lg, const float* __restrict__ lb, bf16* __restrict__ Hout)
{
  const int b = blockIdx.y;
  const int m0 = blockIdx.x * 8;
  const int c = threadIdx.x;
  __shared__ float red[8];
  float lgv = lg[c], lbv = lb[c];
  int wv = c >> 6, ln = c & 63;
  for (int m = 0; m < 8; m++) {
    size_t idx = ((size_t)b * NN + m0 + m) * DM + c;
    float g = 1.f / (1.f + __expf(-b2f(Gp[idx])));
    float u = geluf(b2f(Up[idx]));
    float hn = b2f(Hr[idx]) + g * u;
    float s1 = hn, s2 = hn * hn;
#pragma unroll
    for (int o = 1; o < 64; o <<= 1) { s1 += __shfl_xor(s1, o, 64); s2 += __shfl_xor(s2, o, 64); }
    if (ln == 0) { red[wv] = s1; red[4 + wv] = s2; }
    __syncthreads();
    float sum = red[0] + red[1] + red[2] + red[3];
    float sq  = red[4] + red[5] + red[6] + red[7];
    float mu = sum * (1.f / DM);
    float var = sq * (1.f / DM) - mu * mu;
    float y = (hn - mu) * rsqrtf(var + 1e-5f) * lgv + lbv;
    Hout[idx] = f2b(y);
    __syncthreads();
  }
}

// rh/rd — unchanged (verified).
__global__ __launch_bounds__(256) void rhrd_kernel(
    const bf16* __restrict__ hh, const bf16* __restrict__ hd,
    const float* __restrict__ bhw, const float* __restrict__ bhb,
    const float* __restrict__ bdw, const float* __restrict__ bdb,
    float* __restrict__ rh, float* __restrict__ rd)
{
  int b = blockIdx.x;
  int t = threadIdx.x;
  int n = t & 127;
  bool isD = t >= 128;
  const bf16* row = (isD ? hd : hh) + ((size_t)b * NN + n) * DM;
  const float* wv = isD ? bdw : bhw;
  float s = isD ? bdb[0] : bhb[0];
  for (int k = 0; k < DM; k++) s += b2f(row[k]) * wv[k];
  (isD ? rd : rh)[(size_t)b * NN + n] = s;
}

// scores — unchanged (verified).
__global__ __launch_bounds__(512) void scores_mfma_kernel(
    const bf16* __restrict__ tmp, const bf16* __restrict__ hd,
    const float* __restrict__ rh, const float* __restrict__ rd,
    float* __restrict__ out)
{
  const int b = blockIdx.x;
  const int w = threadIdx.x >> 6;
  const int lane = threadIdx.x & 63;
  const int wr = w >> 1, wc = w & 1;
  const int r16 = lane & 15;
  const int kg = lane >> 4;

  size_t qoff[2], moff[4];
#pragma unroll
  for (int mi = 0; mi < 2; mi++) qoff[mi] = ((size_t)b * NN + wr * 32 + mi * 16 + r16) * DM;
#pragma unroll
  for (int ni = 0; ni < 4; ni++) moff[ni] = ((size_t)b * NN + wc * 64 + ni * 16 + r16) * DM;

  f32x4v zero = {0.f, 0.f, 0.f, 0.f};
  f32x4v acc[2][4];
#pragma unroll
  for (int mi = 0; mi < 2; mi++)
#pragma unroll
    for (int ni = 0; ni < 4; ni++) acc[mi][ni] = zero;

  for (int k0 = 0; k0 < DM; k0 += 32) {
    int k = k0 + kg * 8;
    bf16x8v a[2], bb[4];
#pragma unroll
    for (int mi = 0; mi < 2; mi++) a[mi] = *(const bf16x8v*)(tmp + qoff[mi] + k);
#pragma unroll
    for (int ni = 0; ni < 4; ni++) bb[ni] = *(const bf16x8v*)(hd + moff[ni] + k);
#pragma unroll
    for (int mi = 0; mi < 2; mi++)
#pragma unroll
      for (int ni = 0; ni < 4; ni++)
        acc[mi][ni] = __builtin_amdgcn_mfma_f32_16x16x32_bf16(a[mi], bb[ni], acc[mi][ni], 0, 0, 0);
  }

#pragma unroll
  for (int ni = 0; ni < 4; ni++) {
    int m = wc * 64 + ni * 16 + r16;
    float rhm = rh[b * NN + m];
#pragma unroll
    for (int mi = 0; mi < 2; mi++) {
      int q0 = wr * 32 + mi * 16 + kg * 4;
#pragma unroll
      for (int r = 0; r < 4; r++)
        out[(size_t)b * NN * NN + (size_t)(q0 + r) * NN + m] =
            acc[mi][ni][r] + rhm + rd[b * NN + q0 + r];
    }
  }
}

// ---------------------------------------------------------------------------
extern "C" void kernel_launch(void* const* d_in, const int* in_sizes, int n_in,
                              void* d_out, int out_size, void* d_ws, size_t ws_size,
                              hipStream_t stream) {
  const float* H      = (const float*)d_in[0];
  const int*   ph     = (const int*)  d_in[1];
  const float* mask   = (const float*)d_in[2];
  const float* ha_w   = (const float*)d_in[3];
  const float* ha_b   = (const float*)d_in[4];
  const float* sa_w   = (const float*)d_in[5];
  const float* sa_b   = (const float*)d_in[6];
  const float* ct_w   = (const float*)d_in[7];
  const float* ct_b   = (const float*)d_in[8];
  const float* gate_w = (const float*)d_in[9];
  const float* gate_b = (const float*)d_in[10];
  const float* tr_w   = (const float*)d_in[11];
  const float* tr_b   = (const float*)d_in[12];
  const float* ln_g   = (const float*)d_in[13];
  const float* ln_b   = (const float*)d_in[14];
  const float* ahw    = (const float*)d_in[15];
  const float* ahb    = (const float*)d_in[16];
  const float* adw    = (const float*)d_in[17];
  const float* adb    = (const float*)d_in[18];
  const float* bil    = (const float*)d_in[19];
  const float* bhw    = (const float*)d_in[20];
  const float* bhb    = (const float*)d_in[21];
  const float* bdw    = (const float*)d_in[22];
  const float* bdb    = (const float*)d_in[23];

  const size_t AB = (size_t)BD * NN * DM;  // 8,388,608 elems
  bf16* wsb  = (bf16*)d_ws;
  bf16* Hcur = wsb + 0 * AB;
  bf16* Qa   = wsb + 1 * AB;
  bf16* Ka   = wsb + 2 * AB;   // later mH
  bf16* Va   = wsb + 3 * AB;   // later Gpre; finally bilinear tmp
  bf16* Qs   = wsb + 4 * AB;
  bf16* Ks   = wsb + 5 * AB;   // later mS
  bf16* Vs   = wsb + 6 * AB;   // later Upre
  bf16* mC   = wsb + 7 * AB;
  float* rh  = (float*)(wsb + 8 * AB);
  float* rd  = rh + (size_t)BD * NN;

  // d_out doubles as scratch: 3 regions of AB bf16 each.
  bf16* D0 = (bf16*)d_out;            // CA, then Oa; overwritten by final cvt
  bf16* D1 = D0 + AB;                 // Os; overwritten by final cvt
  bf16* D2 = D0 + 2 * AB;             // wT arena; overwritten by scores at end
  bf16* haT = D2;                     // 4 x 65536
  bf16* saT = D2 + 262144;            // 4 x 65536
  bf16* ctT = D2 + 524288;            // 131072
  bf16* gT  = D2 + 655360;            // 262144
  bf16* tT  = D2 + 917504;            // 262144

  cvt32to16_kernel<<<dim3(2048), 256, 0, stream>>>(H, Hcur, (int)AB);

  for (int r = 0; r < RR; r++) {
    // ---- transpose this round's weights to bf16 [N][K] ----
    TTable T; int base = 0;
    for (int i = 0; i < 4; i++) {
      T.e[i] = { ha_w + ((size_t)r * 4 + i) * 65536, haT + (size_t)i * 65536, 256, base };
      base += 64;
    }
    for (int i = 0; i < 4; i++) {
      T.e[4 + i] = { sa_w + ((size_t)r * 4 + i) * 65536, saT + (size_t)i * 65536, 256, base };
      base += 64;
    }
    T.e[8]  = { ct_w   + (size_t)r * 131072, ctT, 512,  base }; base += 128;
    T.e[9]  = { gate_w + (size_t)r * 262144, gT,  1024, base }; base += 256;
    T.e[10] = { tr_w   + (size_t)r * 262144, tT,  1024, base }; base += 256;
    transpose_w_kernel<<<dim3(base), 256, 0, stream>>>(T, 11);

    // ---- child_avg (CA -> D0) ----
    child_avg2_kernel<<<dim3(BD), 256, 0, stream>>>(Hcur, ph, mask, D0);

    const float* hab = ha_b + (size_t)r * 4 * DM;
    const float* sab = sa_b + (size_t)r * 4 * DM;

    // ---- 7 projection GEMMs in one dispatch ----
    {
      GJobs8 J = {};
      J.j[0] = { Hcur, Hcur, Hcur, Hcur, nullptr, haT,          hab + 0,   Qa, 256, 0, 0 };
      J.j[1] = { Hcur, Hcur, Hcur, Hcur, ph,      haT + 65536,  hab + 256, Ka, 256, 0, 0 };
      J.j[2] = { Hcur, Hcur, Hcur, Hcur, ph,      haT + 131072, hab + 512, Va, 256, 0, 1 };
      J.j[3] = { Hcur, Hcur, Hcur, Hcur, nullptr, saT,          sab + 0,   Qs, 256, 0, 0 };
      J.j[4] = { Hcur, Hcur, Hcur, Hcur, nullptr, saT + 65536,  sab + 256, Ks, 256, 0, 0 };
      J.j[5] = { Hcur, Hcur, Hcur, Hcur, nullptr, saT + 131072, sab + 512, Vs, 256, 0, 1 };
      J.j[6] = { Hcur, D0,   Hcur, Hcur, nullptr, ctT, ct_b + (size_t)r * DM, mC, 512, 1, 0 };
      gemm_multi_kernel<<<dim3(BD, 7), 512, 0, stream>>>(J);
    }

    // ---- both attentions in one dispatch (Oa->D0, Os->D1) ----
    {
      AttnArgs A = { Qa, Ka, Va, D0, Qs, Ks, Vs, D1 };
      attn2_kernel<<<dim3(NHD, BD, 2), 256, 0, stream>>>(A, ph, mask);
    }

    // ---- both output projections (mH->Ka, mS->Ks) ----
    {
      GJobs8 J = {};
      J.j[0] = { D0, D0, D0, D0, nullptr, haT + 196608, hab + 768, Ka, 256, 0, 0 };
      J.j[1] = { D1, D1, D1, D1, nullptr, saT + 196608, sab + 768, Ks, 256, 0, 0 };
      gemm_multi_kernel<<<dim3(BD, 2), 512, 0, stream>>>(J);
    }

    // ---- gate + tr (K=1024) in one dispatch (G->Va, U->Vs) ----
    {
      GJobs8 J = {};
      J.j[0] = { Hcur, Ka, mC, Ks, nullptr, gT, gate_b + (size_t)r * DM, Va, 1024, 0, 0 };
      J.j[1] = { Hcur, Ka, mC, Ks, nullptr, tT, tr_b   + (size_t)r * DM, Vs, 1024, 0, 0 };
      gemm_multi_kernel<<<dim3(BD, 2), 512, 0, stream>>>(J);
    }

    // ---- residual + LN (in-place Hcur) ----
    ln_epi_kernel<<<dim3(16, BD), 256, 0, stream>>>(Hcur, Va, Vs,
        ln_g + (size_t)r * DM, ln_b + (size_t)r * DM, Hcur);
  }

  // ---- final biaffine scorer ----
  {
    TTable T;
    T.e[0] = { ahw, D2,           256, 0 };
    T.e[1] = { adw, D2 + 65536,   256, 64 };
    T.e[2] = { bil, D2 + 131072,  256, 128 };
    transpose_w_kernel<<<dim3(192), 256, 0, stream>>>(T, 3);
  }
  {
    GJobs8 J = {};
    J.j[0] = { Hcur, Hcur, Hcur, Hcur, nullptr, D2,          ahb, Qa, 256, 0, 0 }; // h_head
    J.j[1] = { Hcur, Hcur, Hcur, Hcur, nullptr, D2 + 65536,  adb, Ka, 256, 0, 0 }; // h_dep
    gemm_multi_kernel<<<dim3(BD, 2), 512, 0, stream>>>(J);
  }
  rhrd_kernel<<<dim3(BD), 256, 0, stream>>>(Qa, Ka, bhw, bhb, bdw, bdb, rh, rd);
  {
    GJobs8 J = {};
    J.j[0] = { Qa, Qa, Qa, Qa, nullptr, D2 + 131072, nullptr, Va, 256, 0, 0 };     // h_head @ bilinear
    gemm_multi_kernel<<<dim3(BD, 1), 512, 0, stream>>>(J);
  }
  scores_mfma_kernel<<<dim3(BD), 512, 0, stream>>>(Va, Ka, rh, rd, (float*)d_out + AB);

  cvt16to32_kernel<<<dim3(2048), 256, 0, stream>>>(Hcur, (float*)d_out, (int)AB);
}

// Round 6
// 1027.433 us; speedup vs baseline: 7.2216x; 1.4722x over previous
//
#include <hip/hip_runtime.h>
#include <hip/hip_bf16.h>
#include <math.h>

typedef __hip_bfloat16 bf16;
typedef __attribute__((ext_vector_type(8))) short bf16x8v;
typedef __attribute__((ext_vector_type(4))) float f32x4v;

#define BD 256   // batch
#define NN 128   // tokens
#define DM 256   // model dim
#define NHD 4    // heads
#define HDIM 64  // head dim
#define RR 3     // rounds

__device__ __forceinline__ float b2f(bf16 x) { return __bfloat162float(x); }
__device__ __forceinline__ bf16 f2b(float x) { return __float2bfloat16(x); }
__device__ __forceinline__ float geluf(float x) { return 0.5f * x * (1.f + erff(x * 0.70710678118654752f)); }

// fp32 -> bf16 convert
__global__ __launch_bounds__(256) void cvt32to16_kernel(
    const float* __restrict__ in, bf16* __restrict__ out, int n)
{
  int i = blockIdx.x * 256 + threadIdx.x;
  int stride = gridDim.x * 256;
  for (; i < n; i += stride) out[i] = f2b(in[i]);
}

// bf16 -> fp32
__global__ __launch_bounds__(256) void cvt16to32_kernel(
    const bf16* __restrict__ in, float* __restrict__ out, int n)
{
  int i = blockIdx.x * 256 + threadIdx.x;
  int stride = gridDim.x * 256;
  for (; i < n; i += stride) out[i] = b2f(in[i]);
}

// ---------------------------------------------------------------------------
// Batched weight transpose: src fp32 [K][256] row-major -> dst bf16 [256][K].
// ---------------------------------------------------------------------------
struct TDesc { const float* src; bf16* dst; int K; int base; };
struct TTable { TDesc e[11]; };

__global__ __launch_bounds__(256) void transpose_w_kernel(TTable T, int nent)
{
  int t = blockIdx.x;
  int ei = 0;
  for (int i = 1; i < nent; i++) if (t >= T.e[i].base) ei = i;
  const float* src = T.e[ei].src;
  bf16* dst = T.e[ei].dst;
  int K = T.e[ei].K;
  int lt = t - T.e[ei].base;
  int nt = lt & 7, kt = lt >> 3;

  __shared__ float tile[32][33];
  int tx = threadIdx.x & 31, ty = threadIdx.x >> 5;
#pragma unroll
  for (int i = 0; i < 4; i++)
    tile[ty + i * 8][tx] = src[(size_t)(kt * 32 + ty + i * 8) * 256 + nt * 32 + tx];
  __syncthreads();
#pragma unroll
  for (int i = 0; i < 4; i++)
    dst[(size_t)(nt * 32 + ty + i * 8) * K + kt * 32 + tx] = f2b(tile[tx][ty + i * 8]);
}

// ---------------------------------------------------------------------------
// Multi-job MFMA GEMM with LDS double-buffered 2-phase pipeline.
// out[b,m,c] = act( sum_k A[b,row(m),k] * Wt[c][k] + bias[c] )
// transp=1: out[b,c,m] (for V^T used by attention).
// Block 512 = 8 waves; tile M=128 x N=256; BK=32.
// LDS: A buf 2x8KB @ 0/8192, W buf 2x16KB @ 16384/32768.
// Swizzle (both ds_write and ds_read): byte = (row*64 + kc*16) ^ ((row&7)<<4)
//   -> 2-way bank aliasing only (free).
// ---------------------------------------------------------------------------
struct GJob {
  const bf16 *a0, *a1, *a2, *a3;   // K/256 segments of A
  const int* gather;
  const bf16* Wt;
  const float* bias;
  bf16* out;
  int K, act, transp;
};
struct GJobs8 { GJob j[8]; };

__global__ __launch_bounds__(512) void gemm_multi_kernel(GJobs8 J)
{
  const GJob jb = J.j[blockIdx.y];
  const int b = blockIdx.x;
  const int tid = threadIdx.x;
  const int w = tid >> 6;
  const int lane = tid & 63;
  const int wr = w >> 2, wc = w & 3;
  const int r16 = lane & 15;
  const int kg = lane >> 4;
  const int K = jb.K;
  const int nk = K >> 5;

  __shared__ __align__(16) char lds[49152];

  const bf16* sp[4] = { jb.a0, jb.a1, jb.a2, jb.a3 };

  // ---- staging mapping: thread -> (row 0..127, 16B k-chunk 0..3) ----
  const int srow = tid >> 2;
  const int skc  = tid & 3;
  int grow = srow;
  if (jb.gather) { int g = jb.gather[b * NN + srow]; grow = min(max(g, 0), NN - 1); }
  const size_t aoff = ((size_t)b * NN + grow) * DM;
  const int s_lds = (srow * 64 + skc * 16) ^ ((srow & 7) << 4);
  const size_t w0off = (size_t)srow * K;
  const size_t w1off = (size_t)(srow + 128) * K;   // cols 128..255 land at s_lds + 8192

  // ---- fragment read offsets (same swizzle) ----
  int a_ro[4], w_ro[4];
#pragma unroll
  for (int mi = 0; mi < 4; mi++) {
    int row = wr * 64 + mi * 16 + r16;
    a_ro[mi] = (row * 64 + kg * 16) ^ ((row & 7) << 4);
  }
#pragma unroll
  for (int ni = 0; ni < 4; ni++) {
    int col = wc * 64 + ni * 16 + r16;
    w_ro[ni] = (col * 64 + kg * 16) ^ ((col & 7) << 4);
  }

  f32x4v zero = {0.f, 0.f, 0.f, 0.f};
  f32x4v acc[4][4];
#pragma unroll
  for (int mi = 0; mi < 4; mi++)
#pragma unroll
    for (int ni = 0; ni < 4; ni++) acc[mi][ni] = zero;

  // ---- prologue: stage k-step 0 into buf0 ----
  {
    bf16x8v av  = *(const bf16x8v*)(sp[0] + aoff + skc * 8);
    bf16x8v w0  = *(const bf16x8v*)(jb.Wt + w0off + skc * 8);
    bf16x8v w1  = *(const bf16x8v*)(jb.Wt + w1off + skc * 8);
    *(bf16x8v*)(lds + 0     + s_lds) = av;
    *(bf16x8v*)(lds + 16384 + s_lds) = w0;
    *(bf16x8v*)(lds + 24576 + s_lds) = w1;
  }
  __syncthreads();

  int cura = 0, curw = 16384;
  for (int kt = 0; kt < nk; kt++) {
    const bool pf = (kt + 1 < nk);
    bf16x8v avn, w0n, w1n;
    if (pf) {
      int k0 = (kt + 1) << 5;
      const bf16* Ab = sp[k0 >> 8];
      avn = *(const bf16x8v*)(Ab + aoff + (k0 & 255) + skc * 8);
      w0n = *(const bf16x8v*)(jb.Wt + w0off + k0 + skc * 8);
      w1n = *(const bf16x8v*)(jb.Wt + w1off + k0 + skc * 8);
    }

    bf16x8v a[4], ww[4];
#pragma unroll
    for (int mi = 0; mi < 4; mi++) a[mi] = *(bf16x8v*)(lds + cura + a_ro[mi]);
#pragma unroll
    for (int ni = 0; ni < 4; ni++) ww[ni] = *(bf16x8v*)(lds + curw + w_ro[ni]);
#pragma unroll
    for (int mi = 0; mi < 4; mi++)
#pragma unroll
      for (int ni = 0; ni < 4; ni++)
        acc[mi][ni] = __builtin_amdgcn_mfma_f32_16x16x32_bf16(a[mi], ww[ni], acc[mi][ni], 0, 0, 0);

    if (pf) {
      __syncthreads();                 // all reads of buf[cur] done block-wide
      int na = cura ^ 8192;
      int nw = curw ^ 49152;           // 16384 <-> 32768
      *(bf16x8v*)(lds + na + s_lds) = avn;
      *(bf16x8v*)(lds + nw + s_lds) = w0n;
      *(bf16x8v*)(lds + nw + 8192 + s_lds) = w1n;
      __syncthreads();                 // staged data visible
      cura = na; curw = nw;
    }
  }

  // ---- epilogue ----
#pragma unroll
  for (int ni = 0; ni < 4; ni++) {
    int col = wc * 64 + ni * 16 + r16;
    float bv = jb.bias ? jb.bias[col] : 0.f;
#pragma unroll
    for (int mi = 0; mi < 4; mi++) {
      int row0 = wr * 64 + mi * 16 + kg * 4;
      if (!jb.transp) {
        size_t base = ((size_t)b * NN + row0) * DM + col;
#pragma unroll
        for (int r = 0; r < 4; r++) {
          float x = acc[mi][ni][r] + bv;
          if (jb.act == 1) x = geluf(x);
          jb.out[base + (size_t)r * DM] = f2b(x);
        }
      } else {
        size_t base = ((size_t)b * DM + col) * NN + row0;
#pragma unroll
        for (int r = 0; r < 4; r++) {
          float x = acc[mi][ni][r] + bv;
          if (jb.act == 1) x = geluf(x);
          jb.out[base + r] = f2b(x);
        }
      }
    }
  }
}

// ---------------------------------------------------------------------------
// Fused dual MFMA attention. blockIdx.z: 0 = head-attn (no mask), 1 = sibling.
// Q,K bf16 [B,N,256] (head slice h*64), V bf16 [B,256,N] pre-transposed.
// block 256 = 4 waves; wave w owns q-rows w*32..w*32+31.
// ---------------------------------------------------------------------------
struct AttnArgs {
  const bf16 *Qa, *Ka, *Va; bf16* Oa;
  const bf16 *Qs, *Ks, *Vs; bf16* Os;
};

__global__ __launch_bounds__(256) void attn2_kernel(
    AttnArgs A, const int* __restrict__ ph, const float* __restrict__ mask)
{
  const int b = blockIdx.y, h = blockIdx.x;
  const bool has_mask = (blockIdx.z == 1);
  const bf16* Qb = has_mask ? A.Qs : A.Qa;
  const bf16* Kb = has_mask ? A.Ks : A.Ka;
  const bf16* Vt = has_mask ? A.Vs : A.Va;
  bf16* Ob       = has_mask ? A.Os : A.Oa;

  const int w = threadIdx.x >> 6;
  const int lane = threadIdx.x & 63;
  const int r16 = lane & 15, kg = lane >> 4;
  const int q0 = w * 32;

  __shared__ bf16 P_lds[4][32 * 128];   // per-wave P tile, XOR-swizzled
  __shared__ int   ph_sh[NN];
  __shared__ float mk_sh[NN];

  if (has_mask && threadIdx.x < NN) {
    ph_sh[threadIdx.x] = ph[(size_t)b * NN + threadIdx.x];
    mk_sh[threadIdx.x] = mask[(size_t)b * NN + threadIdx.x];
  }
  __syncthreads();

  const bf16* Qh = Qb + (size_t)b * NN * DM + (size_t)h * HDIM;
  const bf16* Kh = Kb + (size_t)b * NN * DM + (size_t)h * HDIM;
  const bf16* Vh = Vt + ((size_t)b * DM + (size_t)h * HDIM) * NN;

  f32x4v zero = {0.f, 0.f, 0.f, 0.f};

  // ---- S = Q K^T ----
  f32x4v accs[2][8];
#pragma unroll
  for (int mi = 0; mi < 2; mi++)
#pragma unroll
    for (int ni = 0; ni < 8; ni++) accs[mi][ni] = zero;

#pragma unroll
  for (int ks = 0; ks < 2; ks++) {
    int d = ks * 32 + kg * 8;
    bf16x8v a[2], bb[8];
#pragma unroll
    for (int mi = 0; mi < 2; mi++)
      a[mi] = *(const bf16x8v*)(Qh + (size_t)(q0 + mi * 16 + r16) * DM + d);
#pragma unroll
    for (int ni = 0; ni < 8; ni++)
      bb[ni] = *(const bf16x8v*)(Kh + (size_t)(ni * 16 + r16) * DM + d);
#pragma unroll
    for (int mi = 0; mi < 2; mi++)
#pragma unroll
      for (int ni = 0; ni < 8; ni++)
        accs[mi][ni] = __builtin_amdgcn_mfma_f32_16x16x32_bf16(a[mi], bb[ni], accs[mi][ni], 0, 0, 0);
  }

  // ---- softmax (row spread over 16-lane group) ----
#pragma unroll
  for (int mi = 0; mi < 2; mi++) {
#pragma unroll
    for (int r = 0; r < 4; r++) {
      int wq = mi * 16 + kg * 4 + r;
      int q_e = q0 + wq;
      float v[8];
      float mx = -3.0e38f;
      int qp = 0; float qm = 1.f;
      if (has_mask) { qp = ph_sh[q_e]; qm = mk_sh[q_e]; }
#pragma unroll
      for (int ni = 0; ni < 8; ni++) {
        float s = accs[mi][ni][r] * 0.125f;
        if (has_mask) {
          int t_e = ni * 16 + r16;
          bool sib = (qp == ph_sh[t_e]) && (q_e != t_e) && (qm > 0.f) && (mk_sh[t_e] > 0.f);
          if (!sib) s = -1e9f;
        }
        v[ni] = s;
        mx = fmaxf(mx, s);
      }
#pragma unroll
      for (int o = 1; o < 16; o <<= 1) mx = fmaxf(mx, __shfl_xor(mx, o, 64));
      float sum = 0.f;
#pragma unroll
      for (int ni = 0; ni < 8; ni++) { v[ni] = __expf(v[ni] - mx); sum += v[ni]; }
#pragma unroll
      for (int o = 1; o < 16; o <<= 1) sum += __shfl_xor(sum, o, 64);
      float inv = 1.f / sum;
      int swz = (wq & 7) << 3;
#pragma unroll
      for (int ni = 0; ni < 8; ni++) {
        int t_e = ni * 16 + r16;
        P_lds[w][(wq * 128 + t_e) ^ swz] = f2b(v[ni] * inv);
      }
    }
  }
  __syncthreads();

  // ---- O = P V ----
  f32x4v acco[2][4];
#pragma unroll
  for (int mi = 0; mi < 2; mi++)
#pragma unroll
    for (int ni = 0; ni < 4; ni++) acco[mi][ni] = zero;

#pragma unroll
  for (int kt = 0; kt < 4; kt++) {
    int t = kt * 32 + kg * 8;
    bf16x8v a[2], bb[4];
#pragma unroll
    for (int mi = 0; mi < 2; mi++) {
      int wqr = mi * 16 + r16;
      int idx = (wqr * 128 + t) ^ ((wqr & 7) << 3);
      a[mi] = *(const bf16x8v*)&P_lds[w][idx];
    }
#pragma unroll
    for (int ni = 0; ni < 4; ni++)
      bb[ni] = *(const bf16x8v*)(Vh + (size_t)(ni * 16 + r16) * NN + t);
#pragma unroll
    for (int mi = 0; mi < 2; mi++)
#pragma unroll
      for (int ni = 0; ni < 4; ni++)
        acco[mi][ni] = __builtin_amdgcn_mfma_f32_16x16x32_bf16(a[mi], bb[ni], acco[mi][ni], 0, 0, 0);
  }

#pragma unroll
  for (int ni = 0; ni < 4; ni++) {
    int d = ni * 16 + r16;
#pragma unroll
    for (int mi = 0; mi < 2; mi++) {
      int qrow = q0 + mi * 16 + kg * 4;
      size_t base = ((size_t)b * NN + qrow) * DM + (size_t)h * HDIM + d;
#pragma unroll
      for (int r = 0; r < 4; r++)
        Ob[base + (size_t)r * DM] = f2b(acco[mi][ni][r]);
    }
  }
}

// ---------------------------------------------------------------------------
// child_avg v2: one block per batch. Deterministic stable counting sort of
// children (n sorted by head m, then by n), then one pass over Hr rows.
// ---------------------------------------------------------------------------
__global__ __launch_bounds__(256) void child_avg2_kernel(
    const bf16* __restrict__ Hr, const int* __restrict__ ph,
    const float* __restrict__ mask, bf16* __restrict__ CA)
{
  const int b = blockIdx.x;
  const int t = threadIdx.x;
  __shared__ int hi[NN];
  __shared__ float mk[NN];
  __shared__ int cnt[NN], off[NN], rnk[NN], lst[NN];
  __shared__ float cntf[NN];

  if (t < NN) {
    int g = ph[(size_t)b * NN + t];
    hi[t] = min(max(g, 0), NN - 1);
    mk[t] = mask[(size_t)b * NN + t];
  }
  __syncthreads();
  if (t < NN) {
    int c = 0, r = 0; float cf = 0.f;
    int me = hi[t];
    for (int j = 0; j < NN; j++) {
      int hj = hi[j];
      c  += (hj == t);
      cf += (hj == t) ? mk[j] : 0.f;
      r  += (j < t) && (hj == me);
    }
    cnt[t] = c; cntf[t] = cf; rnk[t] = r;
  }
  __syncthreads();
  if (t < NN) {
    int o = 0;
    for (int m = 0; m < t; m++) o += cnt[m];
    off[t] = o;
  }
  __syncthreads();
  if (t < NN) lst[off[hi[t]] + rnk[t]] = t;
  __syncthreads();

  const bf16* Hb = Hr + (size_t)b * NN * DM;
  bf16* Cb = CA + (size_t)b * NN * DM;
  const int d = t;   // 256 threads = 256 columns
  for (int m = 0; m < NN; m++) {
    float s = 0.f;
    int o = off[m], c = cnt[m];
    for (int i = 0; i < c; i++)
      s += b2f(Hb[(size_t)lst[o + i] * DM + d]);
    Cb[(size_t)m * DM + d] = f2b(s / fmaxf(cntf[m], 1.f));
  }
}

// ---------------------------------------------------------------------------
// LN epilogue — unchanged (verified).
// ---------------------------------------------------------------------------
__global__ __launch_bounds__(256) void ln_epi_kernel(
    const bf16* __restrict__ Hr, const bf16* __restrict__ Gp, const bf16* __restrict__ Up,
    const float* __restrict__ lg, const float* __restrict__ lb, bf16* __restrict__ Hout)
{
  const int b = blockIdx.y;
  const int m0 = blockIdx.x * 8;
  const int c = threadIdx.x;
  __shared__ float red[8];
  float lgv = lg[c], lbv = lb[c];
  int wv = c >> 6, ln = c & 63;
  for (int m = 0; m < 8; m++) {
    size_t idx = ((size_t)b * NN + m0 + m) * DM + c;
    float g = 1.f / (1.f + __expf(-b2f(Gp[idx])));
    float u = geluf(b2f(Up[idx]));
    float hn = b2f(Hr[idx]) + g * u;
    float s1 = hn, s2 = hn * hn;
#pragma unroll
    for (int o = 1; o < 64; o <<= 1) { s1 += __shfl_xor(s1, o, 64); s2 += __shfl_xor(s2, o, 64); }
    if (ln == 0) { red[wv] = s1; red[4 + wv] = s2; }
    __syncthreads();
    float sum = red[0] + red[1] + red[2] + red[3];
    float sq  = red[4] + red[5] + red[6] + red[7];
    float mu = sum * (1.f / DM);
    float var = sq * (1.f / DM) - mu * mu;
    float y = (hn - mu) * rsqrtf(var + 1e-5f) * lgv + lbv;
    Hout[idx] = f2b(y);
    __syncthreads();
  }
}

// rh/rd — unchanged (verified).
__global__ __launch_bounds__(256) void rhrd_kernel(
    const bf16* __restrict__ hh, const bf16* __restrict__ hd,
    const float* __restrict__ bhw, const float* __restrict__ bhb,
    const float* __restrict__ bdw, const float* __restrict__ bdb,
    float* __restrict__ rh, float* __restrict__ rd)
{
  int b = blockIdx.x;
  int t = threadIdx.x;
  int n = t & 127;
  bool isD = t >= 128;
  const bf16* row = (isD ? hd : hh) + ((size_t)b * NN + n) * DM;
  const float* wv = isD ? bdw : bhw;
  float s = isD ? bdb[0] : bhb[0];
  for (int k = 0; k < DM; k++) s += b2f(row[k]) * wv[k];
  (isD ? rd : rh)[(size_t)b * NN + n] = s;
}

// scores — unchanged (verified).
__global__ __launch_bounds__(512) void scores_mfma_kernel(
    const bf16* __restrict__ tmp, const bf16* __restrict__ hd,
    const float* __restrict__ rh, const float* __restrict__ rd,
    float* __restrict__ out)
{
  const int b = blockIdx.x;
  const int w = threadIdx.x >> 6;
  const int lane = threadIdx.x & 63;
  const int wr = w >> 1, wc = w & 1;
  const int r16 = lane & 15;
  const int kg = lane >> 4;

  size_t qoff[2], moff[4];
#pragma unroll
  for (int mi = 0; mi < 2; mi++) qoff[mi] = ((size_t)b * NN + wr * 32 + mi * 16 + r16) * DM;
#pragma unroll
  for (int ni = 0; ni < 4; ni++) moff[ni] = ((size_t)b * NN + wc * 64 + ni * 16 + r16) * DM;

  f32x4v zero = {0.f, 0.f, 0.f, 0.f};
  f32x4v acc[2][4];
#pragma unroll
  for (int mi = 0; mi < 2; mi++)
#pragma unroll
    for (int ni = 0; ni < 4; ni++) acc[mi][ni] = zero;

  for (int k0 = 0; k0 < DM; k0 += 32) {
    int k = k0 + kg * 8;
    bf16x8v a[2], bb[4];
#pragma unroll
    for (int mi = 0; mi < 2; mi++) a[mi] = *(const bf16x8v*)(tmp + qoff[mi] + k);
#pragma unroll
    for (int ni = 0; ni < 4; ni++) bb[ni] = *(const bf16x8v*)(hd + moff[ni] + k);
#pragma unroll
    for (int mi = 0; mi < 2; mi++)
#pragma unroll
      for (int ni = 0; ni < 4; ni++)
        acc[mi][ni] = __builtin_amdgcn_mfma_f32_16x16x32_bf16(a[mi], bb[ni], acc[mi][ni], 0, 0, 0);
  }

#pragma unroll
  for (int ni = 0; ni < 4; ni++) {
    int m = wc * 64 + ni * 16 + r16;
    float rhm = rh[b * NN + m];
#pragma unroll
    for (int mi = 0; mi < 2; mi++) {
      int q0 = wr * 32 + mi * 16 + kg * 4;
#pragma unroll
      for (int r = 0; r < 4; r++)
        out[(size_t)b * NN * NN + (size_t)(q0 + r) * NN + m] =
            acc[mi][ni][r] + rhm + rd[b * NN + q0 + r];
    }
  }
}

// ---------------------------------------------------------------------------
extern "C" void kernel_launch(void* const* d_in, const int* in_sizes, int n_in,
                              void* d_out, int out_size, void* d_ws, size_t ws_size,
                              hipStream_t stream) {
  const float* H      = (const float*)d_in[0];
  const int*   ph     = (const int*)  d_in[1];
  const float* mask   = (const float*)d_in[2];
  const float* ha_w   = (const float*)d_in[3];
  const float* ha_b   = (const float*)d_in[4];
  const float* sa_w   = (const float*)d_in[5];
  const float* sa_b   = (const float*)d_in[6];
  const float* ct_w   = (const float*)d_in[7];
  const float* ct_b   = (const float*)d_in[8];
  const float* gate_w = (const float*)d_in[9];
  const float* gate_b = (const float*)d_in[10];
  const float* tr_w   = (const float*)d_in[11];
  const float* tr_b   = (const float*)d_in[12];
  const float* ln_g   = (const float*)d_in[13];
  const float* ln_b   = (const float*)d_in[14];
  const float* ahw    = (const float*)d_in[15];
  const float* ahb    = (const float*)d_in[16];
  const float* adw    = (const float*)d_in[17];
  const float* adb    = (const float*)d_in[18];
  const float* bil    = (const float*)d_in[19];
  const float* bhw    = (const float*)d_in[20];
  const float* bhb    = (const float*)d_in[21];
  const float* bdw    = (const float*)d_in[22];
  const float* bdb    = (const float*)d_in[23];

  const size_t AB = (size_t)BD * NN * DM;  // 8,388,608 elems
  bf16* wsb  = (bf16*)d_ws;
  bf16* Hcur = wsb + 0 * AB;
  bf16* Qa   = wsb + 1 * AB;
  bf16* Ka   = wsb + 2 * AB;   // later mH
  bf16* Va   = wsb + 3 * AB;   // later Gpre; finally bilinear tmp
  bf16* Qs   = wsb + 4 * AB;
  bf16* Ks   = wsb + 5 * AB;   // later mS
  bf16* Vs   = wsb + 6 * AB;   // later Upre
  bf16* mC   = wsb + 7 * AB;
  float* rh  = (float*)(wsb + 8 * AB);
  float* rd  = rh + (size_t)BD * NN;

  // d_out doubles as scratch: 3 regions of AB bf16 each.
  bf16* D0 = (bf16*)d_out;            // CA, then Oa; overwritten by final cvt
  bf16* D1 = D0 + AB;                 // Os; overwritten by final cvt
  bf16* D2 = D0 + 2 * AB;             // wT arena; overwritten by scores at end
  bf16* haT = D2;                     // 4 x 65536
  bf16* saT = D2 + 262144;            // 4 x 65536
  bf16* ctT = D2 + 524288;            // 131072
  bf16* gT  = D2 + 655360;            // 262144
  bf16* tT  = D2 + 917504;            // 262144

  cvt32to16_kernel<<<dim3(2048), 256, 0, stream>>>(H, Hcur, (int)AB);

  for (int r = 0; r < RR; r++) {
    // ---- transpose this round's weights to bf16 [N][K] ----
    TTable T; int base = 0;
    for (int i = 0; i < 4; i++) {
      T.e[i] = { ha_w + ((size_t)r * 4 + i) * 65536, haT + (size_t)i * 65536, 256, base };
      base += 64;
    }
    for (int i = 0; i < 4; i++) {
      T.e[4 + i] = { sa_w + ((size_t)r * 4 + i) * 65536, saT + (size_t)i * 65536, 256, base };
      base += 64;
    }
    T.e[8]  = { ct_w   + (size_t)r * 131072, ctT, 512,  base }; base += 128;
    T.e[9]  = { gate_w + (size_t)r * 262144, gT,  1024, base }; base += 256;
    T.e[10] = { tr_w   + (size_t)r * 262144, tT,  1024, base }; base += 256;
    transpose_w_kernel<<<dim3(base), 256, 0, stream>>>(T, 11);

    // ---- child_avg (CA -> D0) ----
    child_avg2_kernel<<<dim3(BD), 256, 0, stream>>>(Hcur, ph, mask, D0);

    const float* hab = ha_b + (size_t)r * 4 * DM;
    const float* sab = sa_b + (size_t)r * 4 * DM;

    // ---- 7 projection GEMMs in one dispatch ----
    {
      GJobs8 J = {};
      J.j[0] = { Hcur, Hcur, Hcur, Hcur, nullptr, haT,          hab + 0,   Qa, 256, 0, 0 };
      J.j[1] = { Hcur, Hcur, Hcur, Hcur, ph,      haT + 65536,  hab + 256, Ka, 256, 0, 0 };
      J.j[2] = { Hcur, Hcur, Hcur, Hcur, ph,      haT + 131072, hab + 512, Va, 256, 0, 1 };
      J.j[3] = { Hcur, Hcur, Hcur, Hcur, nullptr, saT,          sab + 0,   Qs, 256, 0, 0 };
      J.j[4] = { Hcur, Hcur, Hcur, Hcur, nullptr, saT + 65536,  sab + 256, Ks, 256, 0, 0 };
      J.j[5] = { Hcur, Hcur, Hcur, Hcur, nullptr, saT + 131072, sab + 512, Vs, 256, 0, 1 };
      J.j[6] = { Hcur, D0,   Hcur, Hcur, nullptr, ctT, ct_b + (size_t)r * DM, mC, 512, 1, 0 };
      gemm_multi_kernel<<<dim3(BD, 7), 512, 0, stream>>>(J);
    }

    // ---- both attentions in one dispatch (Oa->D0, Os->D1) ----
    {
      AttnArgs A = { Qa, Ka, Va, D0, Qs, Ks, Vs, D1 };
      attn2_kernel<<<dim3(NHD, BD, 2), 256, 0, stream>>>(A, ph, mask);
    }

    // ---- both output projections (mH->Ka, mS->Ks) ----
    {
      GJobs8 J = {};
      J.j[0] = { D0, D0, D0, D0, nullptr, haT + 196608, hab + 768, Ka, 256, 0, 0 };
      J.j[1] = { D1, D1, D1, D1, nullptr, saT + 196608, sab + 768, Ks, 256, 0, 0 };
      gemm_multi_kernel<<<dim3(BD, 2), 512, 0, stream>>>(J);
    }

    // ---- gate + tr (K=1024) in one dispatch (G->Va, U->Vs) ----
    {
      GJobs8 J = {};
      J.j[0] = { Hcur, Ka, mC, Ks, nullptr, gT, gate_b + (size_t)r * DM, Va, 1024, 0, 0 };
      J.j[1] = { Hcur, Ka, mC, Ks, nullptr, tT, tr_b   + (size_t)r * DM, Vs, 1024, 0, 0 };
      gemm_multi_kernel<<<dim3(BD, 2), 512, 0, stream>>>(J);
    }

    // ---- residual + LN (in-place Hcur) ----
    ln_epi_kernel<<<dim3(16, BD), 256, 0, stream>>>(Hcur, Va, Vs,
        ln_g + (size_t)r * DM, ln_b + (size_t)r * DM, Hcur);
  }

  // ---- final biaffine scorer ----
  {
    TTable T;
    T.e[0] = { ahw, D2,           256, 0 };
    T.e[1] = { adw, D2 + 65536,   256, 64 };
    T.e[2] = { bil, D2 + 131072,  256, 128 };
    transpose_w_kernel<<<dim3(192), 256, 0, stream>>>(T, 3);
  }
  {
    GJobs8 J = {};
    J.j[0] = { Hcur, Hcur, Hcur, Hcur, nullptr, D2,          ahb, Qa, 256, 0, 0 }; // h_head
    J.j[1] = { Hcur, Hcur, Hcur, Hcur, nullptr, D2 + 65536,  adb, Ka, 256, 0, 0 }; // h_dep
    gemm_multi_kernel<<<dim3(BD, 2), 512, 0, stream>>>(J);
  }
  rhrd_kernel<<<dim3(BD), 256, 0, stream>>>(Qa, Ka, bhw, bhb, bdw, bdb, rh, rd);
  {
    GJobs8 J = {};
    J.j[0] = { Qa, Qa, Qa, Qa, nullptr, D2 + 131072, nullptr, Va, 256, 0, 0 };     // h_head @ bilinear
    gemm_multi_kernel<<<dim3(BD, 1), 512, 0, stream>>>(J);
  }
  scores_mfma_kernel<<<dim3(BD), 512, 0, stream>>>(Va, Ka, rh, rd, (float*)d_out + AB);

  cvt16to32_kernel<<<dim3(2048), 256, 0, stream>>>(Hcur, (float*)d_out, (int)AB);
}